// Round 1
// baseline (2230.005 us; speedup 1.0000x reference)
//
#include <hip/hip_runtime.h>

#define N_NODES 30000
#define N_EDGES 400000
#define N_TOT   430000   // E + N self loops
#define HID     128
#define NH      4
#define HC      512      // NH * 128
#define NL      3
#define NG      64
#define NEG_SLOPE 0.2f
#define BN_EPS 1e-5f

__device__ __forceinline__ float atomAddF(float* p, float v) { return unsafeAtomicAdd(p, v); }

__device__ __forceinline__ unsigned encf(float x) {
  unsigned u = __float_as_uint(x);
  return (u & 0x80000000u) ? ~u : (u | 0x80000000u);
}
__device__ __forceinline__ float decf(unsigned u) {
  return (u & 0x80000000u) ? __uint_as_float(u ^ 0x80000000u) : __uint_as_float(~u);
}

// ---------------- attention projection precompute ----------------
// wsrc[l][d][h] = sum_c W[l][d][h*128+c] * att_src[l][h][c]   (wdst same with att_dst)
// weatt[l][d][h] = sum_c We[l][d][h*128+c] * att_e[l][h][c],  d < 3
__global__ void prep_att_kernel(const float* __restrict__ W, const float* __restrict__ att_src,
                                const float* __restrict__ att_dst, const float* __restrict__ We,
                                const float* __restrict__ att_e,
                                float* __restrict__ wsrc, float* __restrict__ wdst,
                                float* __restrict__ weatt) {
  int l = blockIdx.x, t = threadIdx.x;   // 128 threads
  for (int h = 0; h < NH; ++h) {
    const float* as = att_src + (size_t)(l*NH + h)*HID;
    const float* ad = att_dst + (size_t)(l*NH + h)*HID;
    const float* wr = W + (size_t)(l*HID + t)*HC + h*HID;
    float s = 0.f, d = 0.f;
    for (int c = 0; c < HID; ++c) { float w = wr[c]; s += w*as[c]; d += w*ad[c]; }
    wsrc[(l*HID + t)*NH + h] = s;
    wdst[(l*HID + t)*NH + h] = d;
  }
  if (t < 3) {
    for (int h = 0; h < NH; ++h) {
      const float* ae = att_e + (size_t)(l*NH + h)*HID;
      const float* wr = We + (size_t)(l*3 + t)*HC + h*HID;
      float s = 0.f;
      for (int c = 0; c < HID; ++c) s += wr[c]*ae[c];
      weatt[(l*3 + t)*NH + h] = s;
    }
  }
}

// in-degree and incoming-edge-attr sum (for self-loop fill_value='mean')
__global__ void deg_easum_kernel(const int* __restrict__ ei, const float* __restrict__ ea,
                                 float* __restrict__ easum, float* __restrict__ deg) {
  int e = blockIdx.x*blockDim.x + threadIdx.x;
  if (e >= N_EDGES) return;
  int d = ei[N_EDGES + e];
  atomAddF(&deg[d], 1.0f);
  atomAddF(&easum[d*3+0], ea[e*3+0]);
  atomAddF(&easum[d*3+1], ea[e*3+1]);
  atomAddF(&easum[d*3+2], ea[e*3+2]);
}

// ---------------- xh = h @ W[l] : [30000,128] x [128,512] ----------------
__global__ __launch_bounds__(256) void gemm_xh_kernel(const float* __restrict__ A,
                                                      const float* __restrict__ B,
                                                      float* __restrict__ C) {
  __shared__ float As[64][68];
  __shared__ float Bs[64][68];
  int m0 = blockIdx.x*64, n0 = blockIdx.y*64;
  int t = threadIdx.x, tx = t & 15, ty = t >> 4;
  float acc[4][4] = {};
  for (int kt = 0; kt < 2; ++kt) {
    #pragma unroll
    for (int i = 0; i < 16; ++i) {
      int idx = t + i*256;
      int m = idx >> 6, k = idx & 63;
      int gm = m0 + m;
      As[m][k] = (gm < N_NODES) ? A[(size_t)gm*HID + kt*64 + k] : 0.f;
      Bs[m][k] = B[(size_t)(kt*64 + m)*HC + n0 + k];  // m plays role of k-row here
    }
    __syncthreads();
    #pragma unroll 8
    for (int k = 0; k < 64; ++k) {
      float a0 = As[ty][k];
      float a1 = As[ty+16][k];
      float a2 = As[ty+32][k];
      float a3 = As[ty+48][k];
      float4 bv = *(const float4*)&Bs[k][tx*4];
      acc[0][0] = fmaf(a0, bv.x, acc[0][0]); acc[0][1] = fmaf(a0, bv.y, acc[0][1]);
      acc[0][2] = fmaf(a0, bv.z, acc[0][2]); acc[0][3] = fmaf(a0, bv.w, acc[0][3]);
      acc[1][0] = fmaf(a1, bv.x, acc[1][0]); acc[1][1] = fmaf(a1, bv.y, acc[1][1]);
      acc[1][2] = fmaf(a1, bv.z, acc[1][2]); acc[1][3] = fmaf(a1, bv.w, acc[1][3]);
      acc[2][0] = fmaf(a2, bv.x, acc[2][0]); acc[2][1] = fmaf(a2, bv.y, acc[2][1]);
      acc[2][2] = fmaf(a2, bv.z, acc[2][2]); acc[2][3] = fmaf(a2, bv.w, acc[2][3]);
      acc[3][0] = fmaf(a3, bv.x, acc[3][0]); acc[3][1] = fmaf(a3, bv.y, acc[3][1]);
      acc[3][2] = fmaf(a3, bv.z, acc[3][2]); acc[3][3] = fmaf(a3, bv.w, acc[3][3]);
    }
    __syncthreads();
  }
  #pragma unroll
  for (int i = 0; i < 4; ++i) {
    int gm = m0 + ty + 16*i;
    if (gm < N_NODES)
      *(float4*)&C[(size_t)gm*HC + n0 + tx*4] =
          make_float4(acc[i][0], acc[i][1], acc[i][2], acc[i][3]);
  }
}

// ---------------- a_s/a_d = h @ wsrc / wdst : one wave per node ----------------
__global__ __launch_bounds__(256) void asd_kernel(const float* __restrict__ hin,
                                                  const float* __restrict__ wsrcL,
                                                  const float* __restrict__ wdstL,
                                                  float* __restrict__ a_s, float* __restrict__ a_d) {
  int wid = (blockIdx.x*256 + threadIdx.x) >> 6;
  int lane = threadIdx.x & 63;
  if (wid >= N_NODES) return;
  float v0 = hin[(size_t)wid*HID + lane];
  float v1 = hin[(size_t)wid*HID + 64 + lane];
  float4 w0s = *(const float4*)&wsrcL[lane*4];
  float4 w1s = *(const float4*)&wsrcL[(64+lane)*4];
  float4 w0d = *(const float4*)&wdstL[lane*4];
  float4 w1d = *(const float4*)&wdstL[(64+lane)*4];
  float ps0 = v0*w0s.x + v1*w1s.x, ps1 = v0*w0s.y + v1*w1s.y;
  float ps2 = v0*w0s.z + v1*w1s.z, ps3 = v0*w0s.w + v1*w1s.w;
  float pd0 = v0*w0d.x + v1*w1d.x, pd1 = v0*w0d.y + v1*w1d.y;
  float pd2 = v0*w0d.z + v1*w1d.z, pd3 = v0*w0d.w + v1*w1d.w;
  #pragma unroll
  for (int off = 32; off > 0; off >>= 1) {
    ps0 += __shfl_xor(ps0, off); ps1 += __shfl_xor(ps1, off);
    ps2 += __shfl_xor(ps2, off); ps3 += __shfl_xor(ps3, off);
    pd0 += __shfl_xor(pd0, off); pd1 += __shfl_xor(pd1, off);
    pd2 += __shfl_xor(pd2, off); pd3 += __shfl_xor(pd3, off);
  }
  if (lane == 0) {
    *(float4*)&a_s[wid*4] = make_float4(ps0, ps1, ps2, ps3);
    *(float4*)&a_d[wid*4] = make_float4(pd0, pd1, pd2, pd3);
  }
}

// ---------------- edge pass: ex = exp(leakyrelu(a_s+a_d+a_e)); den += ex ----------------
__global__ void edge_ex_kernel(const int* __restrict__ ei, const float* __restrict__ ea,
                               const float* __restrict__ easum, const float* __restrict__ deg,
                               const float* __restrict__ a_s, const float* __restrict__ a_d,
                               const float* __restrict__ weattL,
                               float* __restrict__ exbuf, float* __restrict__ den) {
  int e = blockIdx.x*blockDim.x + threadIdx.x;
  if (e >= N_TOT) return;
  int s, d; float e0, e1, e2;
  if (e < N_EDGES) {
    s = ei[e]; d = ei[N_EDGES + e];
    e0 = ea[e*3+0]; e1 = ea[e*3+1]; e2 = ea[e*3+2];
  } else {
    int n = e - N_EDGES; s = n; d = n;
    float inv = 1.f / fmaxf(deg[n], 1.f);
    e0 = easum[n*3+0]*inv; e1 = easum[n*3+1]*inv; e2 = easum[n*3+2]*inv;
  }
  float4 as4 = *(const float4*)&a_s[s*4];
  float4 ad4 = *(const float4*)&a_d[d*4];
  float4 w0 = *(const float4*)&weattL[0];
  float4 w1 = *(const float4*)&weattL[4];
  float4 w2 = *(const float4*)&weattL[8];
  float raw0 = as4.x + ad4.x + e0*w0.x + e1*w1.x + e2*w2.x;
  float raw1 = as4.y + ad4.y + e0*w0.y + e1*w1.y + e2*w2.y;
  float raw2 = as4.z + ad4.z + e0*w0.z + e1*w1.z + e2*w2.z;
  float raw3 = as4.w + ad4.w + e0*w0.w + e1*w1.w + e2*w2.w;
  raw0 = raw0 > 0.f ? raw0 : NEG_SLOPE*raw0;
  raw1 = raw1 > 0.f ? raw1 : NEG_SLOPE*raw1;
  raw2 = raw2 > 0.f ? raw2 : NEG_SLOPE*raw2;
  raw3 = raw3 > 0.f ? raw3 : NEG_SLOPE*raw3;
  float ex0 = __expf(raw0), ex1 = __expf(raw1), ex2 = __expf(raw2), ex3 = __expf(raw3);
  *(float4*)&exbuf[e*4] = make_float4(ex0, ex1, ex2, ex3);
  atomAddF(&den[d*4+0], ex0);
  atomAddF(&den[d*4+1], ex1);
  atomAddF(&den[d*4+2], ex2);
  atomAddF(&den[d*4+3], ex3);
}

// ---------------- scatter: hnext[dst,c] += 0.25 * sum_h alpha * xh[src,h,c] ----------------
__global__ __launch_bounds__(256) void scatter_kernel(const int* __restrict__ ei,
                                                      const float* __restrict__ exbuf,
                                                      const float* __restrict__ den,
                                                      const float* __restrict__ xh,
                                                      float* __restrict__ hnext) {
  int wid = (blockIdx.x*256 + threadIdx.x) >> 6;
  int lane = threadIdx.x & 63;
  if (wid >= N_TOT) return;
  int s, d;
  if (wid < N_EDGES) { s = ei[wid]; d = ei[N_EDGES + wid]; }
  else { s = wid - N_EDGES; d = s; }
  float4 exv = *(const float4*)&exbuf[wid*4];
  float4 dnv = *(const float4*)&den[d*4];
  float c0 = 0.25f*exv.x/dnv.x, c1 = 0.25f*exv.y/dnv.y;
  float c2 = 0.25f*exv.z/dnv.z, c3 = 0.25f*exv.w/dnv.w;
  const float* xr = xh + (size_t)s*HC;
  int cc = lane*2;
  float2 v0 = *(const float2*)&xr[cc];
  float2 v1 = *(const float2*)&xr[128+cc];
  float2 v2 = *(const float2*)&xr[256+cc];
  float2 v3 = *(const float2*)&xr[384+cc];
  float ax = c0*v0.x + c1*v1.x + c2*v2.x + c3*v3.x;
  float ay = c0*v0.y + c1*v1.y + c2*v2.y + c3*v3.y;
  float* hp = hnext + (size_t)d*HID + cc;
  atomAddF(hp, ax);
  atomAddF(hp+1, ay);
}

// ---------------- BatchNorm: column sums / sumsq ----------------
__global__ void bnstats_kernel(const float* __restrict__ hpre,
                               float* __restrict__ colsum, float* __restrict__ colsq) {
  __shared__ float ssum[256], ssq[256];
  int t = threadIdx.x;
  int c = t & 127, half = t >> 7;
  int r0 = blockIdx.x * 64;
  float s = 0.f, q = 0.f;
  for (int j = half; j < 64; j += 2) {
    int r = r0 + j;
    if (r < N_NODES) { float v = hpre[(size_t)r*HID + c]; s += v; q += v*v; }
  }
  ssum[t] = s; ssq[t] = q;
  __syncthreads();
  if (half == 0) {
    atomAddF(&colsum[c], ssum[c] + ssum[c+128]);
    atomAddF(&colsq[c],  ssq[c]  + ssq[c+128]);
  }
}

__global__ void bnfin_kernel(const float* __restrict__ colsum, const float* __restrict__ colsq,
                             const float* __restrict__ gammaL, const float* __restrict__ betaL,
                             float* __restrict__ scale, float* __restrict__ shift) {
  int c = threadIdx.x;
  const float invn = 1.f / (float)N_NODES;
  float mu = colsum[c] * invn;
  float var = fmaxf(colsq[c]*invn - mu*mu, 0.f);
  float sc = gammaL[c] * rsqrtf(var + BN_EPS);
  scale[c] = sc;
  shift[c] = betaL[c] - mu*sc;
}

__global__ void bnapply_kernel(const float* __restrict__ hpre, const float* __restrict__ scale,
                               const float* __restrict__ shift, float* __restrict__ hout) {
  int i = blockIdx.x*blockDim.x + threadIdx.x;      // one float4 per thread
  if (i >= N_NODES*HID/4) return;
  int c4 = (i*4) & 127;
  float4 v = *(const float4*)&hpre[(size_t)i*4];
  float4 sc = *(const float4*)&scale[c4];
  float4 sh = *(const float4*)&shift[c4];
  v.x = fmaxf(fmaf(v.x, sc.x, sh.x), 0.f);
  v.y = fmaxf(fmaf(v.y, sc.y, sh.y), 0.f);
  v.z = fmaxf(fmaf(v.z, sc.z, sh.z), 0.f);
  v.w = fmaxf(fmaf(v.w, sc.w, sh.w), 0.f);
  *(float4*)&hout[(size_t)i*4] = v;
}

// ---------------- node MLP 128->64->32->2 (thread per node) ----------------
__global__ __launch_bounds__(256) void nodemlp_kernel(const float* __restrict__ h,
    const float* __restrict__ w1, const float* __restrict__ b1,
    const float* __restrict__ w2, const float* __restrict__ b2,
    const float* __restrict__ w3, const float* __restrict__ b3,
    float* __restrict__ out) {
  int n = blockIdx.x*256 + threadIdx.x;
  if (n >= N_NODES) return;
  const float* hr = h + (size_t)n*HID;
  float l1[64];
  #pragma unroll
  for (int o = 0; o < 64; ++o) l1[o] = b1[o];
  for (int k4 = 0; k4 < 32; ++k4) {
    float4 hv = *(const float4*)(hr + k4*4);
    const float* wp = &w1[k4*4*64];
    #pragma unroll
    for (int o = 0; o < 64; ++o)
      l1[o] += hv.x*wp[o] + hv.y*wp[64+o] + hv.z*wp[128+o] + hv.w*wp[192+o];
  }
  #pragma unroll
  for (int o = 0; o < 64; ++o) l1[o] = fmaxf(l1[o], 0.f);
  float l2[32];
  #pragma unroll
  for (int o = 0; o < 32; ++o) l2[o] = b2[o];
  for (int k = 0; k < 64; ++k) {
    float hv = l1[k];
    const float* wp = &w2[k*32];
    #pragma unroll
    for (int o = 0; o < 32; ++o) l2[o] += hv*wp[o];
  }
  float o0 = b3[0], o1 = b3[1];
  #pragma unroll
  for (int k = 0; k < 32; ++k) {
    float hv = fmaxf(l2[k], 0.f);
    o0 += hv*w3[k*2]; o1 += hv*w3[k*2+1];
  }
  out[(size_t)n*2]   = o0;
  out[(size_t)n*2+1] = o1;
}

// ---------------- graph pooling ----------------
__global__ void gmax_init_kernel(unsigned* __restrict__ gmaxenc) {
  int i = blockIdx.x*blockDim.x + threadIdx.x;
  if (i < NG*HID) gmaxenc[i] = 0x00800000u;   // enc(-FLT_MAX)
}

__global__ __launch_bounds__(128) void pool_kernel(const float* __restrict__ h,
                                                   const int* __restrict__ batch,
                                                   float* __restrict__ gsum,
                                                   unsigned* __restrict__ gmaxenc,
                                                   float* __restrict__ gcnt) {
  int n = blockIdx.x, t = threadIdx.x;
  int g = batch[n];
  float v = h[(size_t)n*HID + t];
  atomAddF(&gsum[g*HID + t], v);
  atomicMax(&gmaxenc[g*HID + t], encf(v));
  if (t == 0) atomAddF(&gcnt[g], 1.f);
}

// ---------------- graph MLP 256->128->64->2 (block per graph) ----------------
__global__ __launch_bounds__(128) void graphmlp_kernel(const float* __restrict__ gsum,
    const unsigned* __restrict__ gmaxenc, const float* __restrict__ gcnt,
    const float* __restrict__ gw1, const float* __restrict__ gb1,
    const float* __restrict__ gw2, const float* __restrict__ gb2,
    const float* __restrict__ gw3, const float* __restrict__ gb3,
    float* __restrict__ out) {
  __shared__ float gr[256], h1[128], h2[64];
  int g = blockIdx.x, t = threadIdx.x;
  float cnt = fmaxf(gcnt[g], 1.f);
  gr[t] = gsum[g*HID + t] / cnt;
  gr[128 + t] = decf(gmaxenc[g*HID + t]);
  __syncthreads();
  float acc = gb1[t];
  for (int k = 0; k < 256; ++k) acc += gr[k]*gw1[k*HID + t];
  h1[t] = fmaxf(acc, 0.f);
  __syncthreads();
  if (t < 64) {
    float a2 = gb2[t];
    for (int k = 0; k < 128; ++k) a2 += h1[k]*gw2[k*64 + t];
    h2[t] = fmaxf(a2, 0.f);
  }
  __syncthreads();
  if (t < 2) {
    float a3 = gb3[t];
    for (int k = 0; k < 64; ++k) a3 += h2[k]*gw3[k*2 + t];
    out[N_NODES*2 + g*2 + t] = a3;
  }
}

extern "C" void kernel_launch(void* const* d_in, const int* in_sizes, int n_in,
                              void* d_out, int out_size, void* d_ws, size_t ws_size,
                              hipStream_t stream) {
  (void)in_sizes; (void)n_in; (void)out_size; (void)ws_size;
  const float* x       = (const float*)d_in[0];
  const int*   ei      = (const int*)d_in[1];
  const float* ea      = (const float*)d_in[2];
  const int*   batch   = (const int*)d_in[3];
  const float* W       = (const float*)d_in[4];
  const float* att_src = (const float*)d_in[5];
  const float* att_dst = (const float*)d_in[6];
  const float* We      = (const float*)d_in[7];
  const float* att_e   = (const float*)d_in[8];
  // d_in[9] = bias: cancels exactly in train-mode BN (and is zeros) -> unused
  const float* gamma   = (const float*)d_in[10];
  const float* beta    = (const float*)d_in[11];
  const float* nw1 = (const float*)d_in[12]; const float* nb1 = (const float*)d_in[13];
  const float* nw2 = (const float*)d_in[14]; const float* nb2 = (const float*)d_in[15];
  const float* nw3 = (const float*)d_in[16]; const float* nb3 = (const float*)d_in[17];
  const float* gw1 = (const float*)d_in[18]; const float* gb1 = (const float*)d_in[19];
  const float* gw2 = (const float*)d_in[20]; const float* gb2 = (const float*)d_in[21];
  const float* gw3 = (const float*)d_in[22]; const float* gb3 = (const float*)d_in[23];
  float* out = (float*)d_out;

  float* p = (float*)d_ws;
  float* xh    = p; p += (size_t)N_NODES*HC;     // 15.36M floats
  float* hbuf  = p; p += (size_t)N_NODES*HID;    // 3.84M
  float* hnext = p; p += (size_t)N_NODES*HID;    // 3.84M
  float* exbuf = p; p += (size_t)N_TOT*NH;       // 1.72M
  float* den   = p; p += (size_t)N_NODES*NH;
  float* a_s   = p; p += (size_t)N_NODES*NH;
  float* a_d   = p; p += (size_t)N_NODES*NH;
  float* easum = p; p += (size_t)N_NODES*3;
  float* deg   = p; p += (size_t)N_NODES;
  float* wsrc  = p; p += NL*HID*NH;
  float* wdst  = p; p += NL*HID*NH;
  float* weatt = p; p += NL*3*NH;
  float* colsum= p; p += HID;
  float* colsq = p; p += HID;
  float* scale = p; p += HID;
  float* shift = p; p += HID;
  float* gsum  = p; p += NG*HID;
  float* gcnt  = p; p += NG;
  unsigned* gmaxenc = (unsigned*)p; p += NG*HID;

  // once-per-call precompute
  hipMemsetAsync(easum, 0, (size_t)(N_NODES*3 + N_NODES)*sizeof(float), stream); // easum + deg
  prep_att_kernel<<<NL, 128, 0, stream>>>(W, att_src, att_dst, We, att_e, wsrc, wdst, weatt);
  deg_easum_kernel<<<(N_EDGES+255)/256, 256, 0, stream>>>(ei, ea, easum, deg);

  const float* hin = x;
  for (int l = 0; l < NL; ++l) {
    hipMemsetAsync(hnext, 0, (size_t)N_NODES*HID*sizeof(float), stream);
    hipMemsetAsync(den, 0, (size_t)N_NODES*NH*sizeof(float), stream);
    hipMemsetAsync(colsum, 0, 2*HID*sizeof(float), stream);  // colsum + colsq

    dim3 ggrid((N_NODES+63)/64, HC/64);
    gemm_xh_kernel<<<ggrid, 256, 0, stream>>>(hin, W + (size_t)l*HID*HC, xh);
    asd_kernel<<<(N_NODES*64)/256, 256, 0, stream>>>(hin, wsrc + l*HID*NH, wdst + l*HID*NH, a_s, a_d);
    edge_ex_kernel<<<(N_TOT+255)/256, 256, 0, stream>>>(ei, ea, easum, deg, a_s, a_d,
                                                        weatt + l*3*NH, exbuf, den);
    scatter_kernel<<<(N_TOT+3)/4, 256, 0, stream>>>(ei, exbuf, den, xh, hnext);
    bnstats_kernel<<<(N_NODES+63)/64, 256, 0, stream>>>(hnext, colsum, colsq);
    bnfin_kernel<<<1, 128, 0, stream>>>(colsum, colsq, gamma + l*HID, beta + l*HID, scale, shift);
    bnapply_kernel<<<(N_NODES*HID/4+255)/256, 256, 0, stream>>>(hnext, scale, shift, hbuf);
    hin = hbuf;
  }

  nodemlp_kernel<<<(N_NODES+255)/256, 256, 0, stream>>>(hbuf, nw1, nb1, nw2, nb2, nw3, nb3, out);

  hipMemsetAsync(gsum, 0, (size_t)(NG*HID + NG)*sizeof(float), stream);  // gsum + gcnt
  gmax_init_kernel<<<(NG*HID+255)/256, 256, 0, stream>>>(gmaxenc);
  pool_kernel<<<N_NODES, 128, 0, stream>>>(hbuf, batch, gsum, gmaxenc, gcnt);
  graphmlp_kernel<<<NG, 128, 0, stream>>>(gsum, gmaxenc, gcnt, gw1, gb1, gw2, gb2, gw3, gb3, out);
}

// Round 2
// 1299.047 us; speedup vs baseline: 1.7166x; 1.7166x over previous
//
#include <hip/hip_runtime.h>

#define N_NODES 30000
#define N_EDGES 400000
#define N_TOT   430000   // E + N self loops
#define HID     128
#define NH      4
#define HC      512      // NH * 128
#define NL      3
#define NG      64
#define NEG_SLOPE 0.2f
#define BN_EPS 1e-5f

__device__ __forceinline__ float atomAddF(float* p, float v) { return unsafeAtomicAdd(p, v); }

__device__ __forceinline__ unsigned encf(float x) {
  unsigned u = __float_as_uint(x);
  return (u & 0x80000000u) ? ~u : (u | 0x80000000u);
}
__device__ __forceinline__ float decf(unsigned u) {
  return (u & 0x80000000u) ? __uint_as_float(u ^ 0x80000000u) : __uint_as_float(~u);
}

// ---------------- attention projection precompute ----------------
__global__ void prep_att_kernel(const float* __restrict__ W, const float* __restrict__ att_src,
                                const float* __restrict__ att_dst, const float* __restrict__ We,
                                const float* __restrict__ att_e,
                                float* __restrict__ wsrc, float* __restrict__ wdst,
                                float* __restrict__ weatt) {
  int l = blockIdx.x, t = threadIdx.x;   // 128 threads
  for (int h = 0; h < NH; ++h) {
    const float* as = att_src + (size_t)(l*NH + h)*HID;
    const float* ad = att_dst + (size_t)(l*NH + h)*HID;
    const float* wr = W + (size_t)(l*HID + t)*HC + h*HID;
    float s = 0.f, d = 0.f;
    for (int c = 0; c < HID; ++c) { float w = wr[c]; s += w*as[c]; d += w*ad[c]; }
    wsrc[(l*HID + t)*NH + h] = s;
    wdst[(l*HID + t)*NH + h] = d;
  }
  if (t < 3) {
    for (int h = 0; h < NH; ++h) {
      const float* ae = att_e + (size_t)(l*NH + h)*HID;
      const float* wr = We + (size_t)(l*3 + t)*HC + h*HID;
      float s = 0.f;
      for (int c = 0; c < HID; ++c) s += wr[c]*ae[c];
      weatt[(l*3 + t)*NH + h] = s;
    }
  }
}

// in-degree and incoming-edge-attr sum (for self-loop fill_value='mean')
__global__ void deg_easum_kernel(const int* __restrict__ ei, const float* __restrict__ ea,
                                 float* __restrict__ easum, float* __restrict__ deg) {
  int e = blockIdx.x*blockDim.x + threadIdx.x;
  if (e >= N_EDGES) return;
  int d = ei[N_EDGES + e];
  atomAddF(&deg[d], 1.0f);
  atomAddF(&easum[d*3+0], ea[e*3+0]);
  atomAddF(&easum[d*3+1], ea[e*3+1]);
  atomAddF(&easum[d*3+2], ea[e*3+2]);
}

// ---------------- CSR build: rowptr = exclusive scan of deg ----------------
__global__ __launch_bounds__(1024) void scan_kernel(const float* __restrict__ deg,
                                                    int* __restrict__ rowptr,
                                                    int* __restrict__ fill) {
  __shared__ int part[1024];
  int t = threadIdx.x;
  const int CH = (N_NODES + 1023) / 1024;  // 30
  int base = t * CH;
  int s = 0;
  for (int i = 0; i < CH; ++i) {
    int n = base + i;
    if (n < N_NODES) s += (int)deg[n];
  }
  part[t] = s;
  __syncthreads();
  for (int off = 1; off < 1024; off <<= 1) {
    int v = (t >= off) ? part[t - off] : 0;
    __syncthreads();
    if (t >= off) part[t] += v;
    __syncthreads();
  }
  int prefix = (t == 0) ? 0 : part[t-1];
  for (int i = 0; i < CH; ++i) {
    int n = base + i;
    if (n < N_NODES) {
      rowptr[n] = prefix;
      fill[n] = 0;
      prefix += (int)deg[n];
    }
  }
  if (t == 1023) rowptr[N_NODES] = part[1023];
}

__global__ void csr_fill_kernel(const int* __restrict__ ei, const int* __restrict__ rowptr,
                                int* __restrict__ fill, int* __restrict__ csr_src,
                                int* __restrict__ csr_pos) {
  int e = blockIdx.x*blockDim.x + threadIdx.x;
  if (e >= N_EDGES) return;
  int s = ei[e], d = ei[N_EDGES + e];
  int pos = rowptr[d] + atomicAdd(&fill[d], 1);
  csr_src[pos] = s;
  csr_pos[e] = pos;
}

// ---------------- xh = h @ W[l] : [30000,128] x [128,512] ----------------
__global__ __launch_bounds__(256) void gemm_xh_kernel(const float* __restrict__ A,
                                                      const float* __restrict__ B,
                                                      float* __restrict__ C) {
  __shared__ float As[64][68];
  __shared__ float Bs[64][68];
  int m0 = blockIdx.x*64, n0 = blockIdx.y*64;
  int t = threadIdx.x, tx = t & 15, ty = t >> 4;
  float acc[4][4] = {};
  for (int kt = 0; kt < 2; ++kt) {
    #pragma unroll
    for (int i = 0; i < 16; ++i) {
      int idx = t + i*256;
      int m = idx >> 6, k = idx & 63;
      int gm = m0 + m;
      As[m][k] = (gm < N_NODES) ? A[(size_t)gm*HID + kt*64 + k] : 0.f;
      Bs[m][k] = B[(size_t)(kt*64 + m)*HC + n0 + k];
    }
    __syncthreads();
    #pragma unroll 8
    for (int k = 0; k < 64; ++k) {
      float a0 = As[ty][k];
      float a1 = As[ty+16][k];
      float a2 = As[ty+32][k];
      float a3 = As[ty+48][k];
      float4 bv = *(const float4*)&Bs[k][tx*4];
      acc[0][0] = fmaf(a0, bv.x, acc[0][0]); acc[0][1] = fmaf(a0, bv.y, acc[0][1]);
      acc[0][2] = fmaf(a0, bv.z, acc[0][2]); acc[0][3] = fmaf(a0, bv.w, acc[0][3]);
      acc[1][0] = fmaf(a1, bv.x, acc[1][0]); acc[1][1] = fmaf(a1, bv.y, acc[1][1]);
      acc[1][2] = fmaf(a1, bv.z, acc[1][2]); acc[1][3] = fmaf(a1, bv.w, acc[1][3]);
      acc[2][0] = fmaf(a2, bv.x, acc[2][0]); acc[2][1] = fmaf(a2, bv.y, acc[2][1]);
      acc[2][2] = fmaf(a2, bv.z, acc[2][2]); acc[2][3] = fmaf(a2, bv.w, acc[2][3]);
      acc[3][0] = fmaf(a3, bv.x, acc[3][0]); acc[3][1] = fmaf(a3, bv.y, acc[3][1]);
      acc[3][2] = fmaf(a3, bv.z, acc[3][2]); acc[3][3] = fmaf(a3, bv.w, acc[3][3]);
    }
    __syncthreads();
  }
  #pragma unroll
  for (int i = 0; i < 4; ++i) {
    int gm = m0 + ty + 16*i;
    if (gm < N_NODES)
      *(float4*)&C[(size_t)gm*HC + n0 + tx*4] =
          make_float4(acc[i][0], acc[i][1], acc[i][2], acc[i][3]);
  }
}

// ---------------- a_s/a_d : one wave per node ----------------
__global__ __launch_bounds__(256) void asd_kernel(const float* __restrict__ hin,
                                                  const float* __restrict__ wsrcL,
                                                  const float* __restrict__ wdstL,
                                                  float* __restrict__ a_s, float* __restrict__ a_d) {
  int wid = (blockIdx.x*256 + threadIdx.x) >> 6;
  int lane = threadIdx.x & 63;
  if (wid >= N_NODES) return;
  float v0 = hin[(size_t)wid*HID + lane];
  float v1 = hin[(size_t)wid*HID + 64 + lane];
  float4 w0s = *(const float4*)&wsrcL[lane*4];
  float4 w1s = *(const float4*)&wsrcL[(64+lane)*4];
  float4 w0d = *(const float4*)&wdstL[lane*4];
  float4 w1d = *(const float4*)&wdstL[(64+lane)*4];
  float ps0 = v0*w0s.x + v1*w1s.x, ps1 = v0*w0s.y + v1*w1s.y;
  float ps2 = v0*w0s.z + v1*w1s.z, ps3 = v0*w0s.w + v1*w1s.w;
  float pd0 = v0*w0d.x + v1*w1d.x, pd1 = v0*w0d.y + v1*w1d.y;
  float pd2 = v0*w0d.z + v1*w1d.z, pd3 = v0*w0d.w + v1*w1d.w;
  #pragma unroll
  for (int off = 32; off > 0; off >>= 1) {
    ps0 += __shfl_xor(ps0, off); ps1 += __shfl_xor(ps1, off);
    ps2 += __shfl_xor(ps2, off); ps3 += __shfl_xor(ps3, off);
    pd0 += __shfl_xor(pd0, off); pd1 += __shfl_xor(pd1, off);
    pd2 += __shfl_xor(pd2, off); pd3 += __shfl_xor(pd3, off);
  }
  if (lane == 0) {
    *(float4*)&a_s[wid*4] = make_float4(ps0, ps1, ps2, ps3);
    *(float4*)&a_d[wid*4] = make_float4(pd0, pd1, pd2, pd3);
  }
}

// ---------------- edge pass: ex = exp(leakyrelu(...)) written in CSR order ----------------
__global__ void edge_ex_kernel(const int* __restrict__ ei, const float* __restrict__ ea,
                               const float* __restrict__ easum, const float* __restrict__ deg,
                               const float* __restrict__ a_s, const float* __restrict__ a_d,
                               const float* __restrict__ weattL, const int* __restrict__ csr_pos,
                               float* __restrict__ excsr, float* __restrict__ exself) {
  int e = blockIdx.x*blockDim.x + threadIdx.x;
  if (e >= N_TOT) return;
  int s, d; float e0, e1, e2;
  if (e < N_EDGES) {
    s = ei[e]; d = ei[N_EDGES + e];
    e0 = ea[e*3+0]; e1 = ea[e*3+1]; e2 = ea[e*3+2];
  } else {
    int n = e - N_EDGES; s = n; d = n;
    float inv = 1.f / fmaxf(deg[n], 1.f);
    e0 = easum[n*3+0]*inv; e1 = easum[n*3+1]*inv; e2 = easum[n*3+2]*inv;
  }
  float4 as4 = *(const float4*)&a_s[s*4];
  float4 ad4 = *(const float4*)&a_d[d*4];
  float4 w0 = *(const float4*)&weattL[0];
  float4 w1 = *(const float4*)&weattL[4];
  float4 w2 = *(const float4*)&weattL[8];
  float raw0 = as4.x + ad4.x + e0*w0.x + e1*w1.x + e2*w2.x;
  float raw1 = as4.y + ad4.y + e0*w0.y + e1*w1.y + e2*w2.y;
  float raw2 = as4.z + ad4.z + e0*w0.z + e1*w1.z + e2*w2.z;
  float raw3 = as4.w + ad4.w + e0*w0.w + e1*w1.w + e2*w2.w;
  raw0 = raw0 > 0.f ? raw0 : NEG_SLOPE*raw0;
  raw1 = raw1 > 0.f ? raw1 : NEG_SLOPE*raw1;
  raw2 = raw2 > 0.f ? raw2 : NEG_SLOPE*raw2;
  raw3 = raw3 > 0.f ? raw3 : NEG_SLOPE*raw3;
  float4 exv = make_float4(__expf(raw0), __expf(raw1), __expf(raw2), __expf(raw3));
  if (e < N_EDGES) {
    *(float4*)&excsr[(size_t)csr_pos[e]*4] = exv;
  } else {
    *(float4*)&exself[(size_t)(e - N_EDGES)*4] = exv;
  }
}

// ---------------- CSR aggregation: one wave per dst node, no atomics ----------------
__global__ __launch_bounds__(256) void agg_kernel(const int* __restrict__ rowptr,
    const int* __restrict__ csr_src, const float* __restrict__ excsr,
    const float* __restrict__ exself, const float* __restrict__ xh,
    float* __restrict__ hnext) {
  int wid = (blockIdx.x*256 + threadIdx.x) >> 6;   // dst node id
  int lane = threadIdx.x & 63;
  if (wid >= N_NODES) return;
  int p0 = rowptr[wid], p1 = rowptr[wid+1];
  int cc = lane*2;
  float a00, a01, a10, a11, a20, a21, a30, a31;
  float den0, den1, den2, den3;
  {
    float4 exv = *(const float4*)&exself[(size_t)wid*4];
    den0 = exv.x; den1 = exv.y; den2 = exv.z; den3 = exv.w;
    const float* xr = xh + (size_t)wid*HC + cc;
    float2 v0 = *(const float2*)&xr[0];
    float2 v1 = *(const float2*)&xr[128];
    float2 v2 = *(const float2*)&xr[256];
    float2 v3 = *(const float2*)&xr[384];
    a00 = exv.x*v0.x; a01 = exv.x*v0.y;
    a10 = exv.y*v1.x; a11 = exv.y*v1.y;
    a20 = exv.z*v2.x; a21 = exv.z*v2.y;
    a30 = exv.w*v3.x; a31 = exv.w*v3.y;
  }
  for (int p = p0; p < p1; ++p) {
    int s = csr_src[p];
    float4 exv = *(const float4*)&excsr[(size_t)p*4];
    den0 += exv.x; den1 += exv.y; den2 += exv.z; den3 += exv.w;
    const float* xr = xh + (size_t)s*HC + cc;
    float2 v0 = *(const float2*)&xr[0];
    float2 v1 = *(const float2*)&xr[128];
    float2 v2 = *(const float2*)&xr[256];
    float2 v3 = *(const float2*)&xr[384];
    a00 = fmaf(exv.x, v0.x, a00); a01 = fmaf(exv.x, v0.y, a01);
    a10 = fmaf(exv.y, v1.x, a10); a11 = fmaf(exv.y, v1.y, a11);
    a20 = fmaf(exv.z, v2.x, a20); a21 = fmaf(exv.z, v2.y, a21);
    a30 = fmaf(exv.w, v3.x, a30); a31 = fmaf(exv.w, v3.y, a31);
  }
  float i0 = 1.f/den0, i1 = 1.f/den1, i2 = 1.f/den2, i3 = 1.f/den3;
  float x0 = 0.25f*(a00*i0 + a10*i1 + a20*i2 + a30*i3);
  float x1 = 0.25f*(a01*i0 + a11*i1 + a21*i2 + a31*i3);
  *(float2*)&hnext[(size_t)wid*HID + cc] = make_float2(x0, x1);
}

// ---------------- BatchNorm: column sums / sumsq ----------------
__global__ void bnstats_kernel(const float* __restrict__ hpre,
                               float* __restrict__ colsum, float* __restrict__ colsq) {
  __shared__ float ssum[256], ssq[256];
  int t = threadIdx.x;
  int c = t & 127, half = t >> 7;
  int r0 = blockIdx.x * 64;
  float s = 0.f, q = 0.f;
  for (int j = half; j < 64; j += 2) {
    int r = r0 + j;
    if (r < N_NODES) { float v = hpre[(size_t)r*HID + c]; s += v; q += v*v; }
  }
  ssum[t] = s; ssq[t] = q;
  __syncthreads();
  if (half == 0) {
    atomAddF(&colsum[c], ssum[c] + ssum[c+128]);
    atomAddF(&colsq[c],  ssq[c]  + ssq[c+128]);
  }
}

__global__ void bnfin_kernel(const float* __restrict__ colsum, const float* __restrict__ colsq,
                             const float* __restrict__ gammaL, const float* __restrict__ betaL,
                             float* __restrict__ scale, float* __restrict__ shift) {
  int c = threadIdx.x;
  const float invn = 1.f / (float)N_NODES;
  float mu = colsum[c] * invn;
  float var = fmaxf(colsq[c]*invn - mu*mu, 0.f);
  float sc = gammaL[c] * rsqrtf(var + BN_EPS);
  scale[c] = sc;
  shift[c] = betaL[c] - mu*sc;
}

__global__ void bnapply_kernel(const float* __restrict__ hpre, const float* __restrict__ scale,
                               const float* __restrict__ shift, float* __restrict__ hout) {
  int i = blockIdx.x*blockDim.x + threadIdx.x;      // one float4 per thread
  if (i >= N_NODES*HID/4) return;
  int c4 = (i*4) & 127;
  float4 v = *(const float4*)&hpre[(size_t)i*4];
  float4 sc = *(const float4*)&scale[c4];
  float4 sh = *(const float4*)&shift[c4];
  v.x = fmaxf(fmaf(v.x, sc.x, sh.x), 0.f);
  v.y = fmaxf(fmaf(v.y, sc.y, sh.y), 0.f);
  v.z = fmaxf(fmaf(v.z, sc.z, sh.z), 0.f);
  v.w = fmaxf(fmaf(v.w, sc.w, sh.w), 0.f);
  *(float4*)&hout[(size_t)i*4] = v;
}

// ---------------- node MLP 128->64->32->2 (thread per node) ----------------
__global__ __launch_bounds__(256) void nodemlp_kernel(const float* __restrict__ h,
    const float* __restrict__ w1, const float* __restrict__ b1,
    const float* __restrict__ w2, const float* __restrict__ b2,
    const float* __restrict__ w3, const float* __restrict__ b3,
    float* __restrict__ out) {
  int n = blockIdx.x*256 + threadIdx.x;
  if (n >= N_NODES) return;
  const float* hr = h + (size_t)n*HID;
  float l1[64];
  #pragma unroll
  for (int o = 0; o < 64; ++o) l1[o] = b1[o];
  for (int k4 = 0; k4 < 32; ++k4) {
    float4 hv = *(const float4*)(hr + k4*4);
    const float* wp = &w1[k4*4*64];
    #pragma unroll
    for (int o = 0; o < 64; ++o)
      l1[o] += hv.x*wp[o] + hv.y*wp[64+o] + hv.z*wp[128+o] + hv.w*wp[192+o];
  }
  #pragma unroll
  for (int o = 0; o < 64; ++o) l1[o] = fmaxf(l1[o], 0.f);
  float l2[32];
  #pragma unroll
  for (int o = 0; o < 32; ++o) l2[o] = b2[o];
  for (int k = 0; k < 64; ++k) {
    float hv = l1[k];
    const float* wp = &w2[k*32];
    #pragma unroll
    for (int o = 0; o < 32; ++o) l2[o] += hv*wp[o];
  }
  float o0 = b3[0], o1 = b3[1];
  #pragma unroll
  for (int k = 0; k < 32; ++k) {
    float hv = fmaxf(l2[k], 0.f);
    o0 += hv*w3[k*2]; o1 += hv*w3[k*2+1];
  }
  out[(size_t)n*2]   = o0;
  out[(size_t)n*2+1] = o1;
}

// ---------------- graph pooling ----------------
__global__ void gmax_init_kernel(unsigned* __restrict__ gmaxenc) {
  int i = blockIdx.x*blockDim.x + threadIdx.x;
  if (i < NG*HID) gmaxenc[i] = 0x00800000u;   // enc(-FLT_MAX)
}

__global__ __launch_bounds__(128) void pool_kernel(const float* __restrict__ h,
                                                   const int* __restrict__ batch,
                                                   float* __restrict__ gsum,
                                                   unsigned* __restrict__ gmaxenc,
                                                   float* __restrict__ gcnt) {
  int n = blockIdx.x, t = threadIdx.x;
  int g = batch[n];
  float v = h[(size_t)n*HID + t];
  atomAddF(&gsum[g*HID + t], v);
  atomicMax(&gmaxenc[g*HID + t], encf(v));
  if (t == 0) atomAddF(&gcnt[g], 1.f);
}

// ---------------- graph MLP 256->128->64->2 (block per graph) ----------------
__global__ __launch_bounds__(128) void graphmlp_kernel(const float* __restrict__ gsum,
    const unsigned* __restrict__ gmaxenc, const float* __restrict__ gcnt,
    const float* __restrict__ gw1, const float* __restrict__ gb1,
    const float* __restrict__ gw2, const float* __restrict__ gb2,
    const float* __restrict__ gw3, const float* __restrict__ gb3,
    float* __restrict__ out) {
  __shared__ float gr[256], h1[128], h2[64];
  int g = blockIdx.x, t = threadIdx.x;
  float cnt = fmaxf(gcnt[g], 1.f);
  gr[t] = gsum[g*HID + t] / cnt;
  gr[128 + t] = decf(gmaxenc[g*HID + t]);
  __syncthreads();
  float acc = gb1[t];
  for (int k = 0; k < 256; ++k) acc += gr[k]*gw1[k*HID + t];
  h1[t] = fmaxf(acc, 0.f);
  __syncthreads();
  if (t < 64) {
    float a2 = gb2[t];
    for (int k = 0; k < 128; ++k) a2 += h1[k]*gw2[k*64 + t];
    h2[t] = fmaxf(a2, 0.f);
  }
  __syncthreads();
  if (t < 2) {
    float a3 = gb3[t];
    for (int k = 0; k < 64; ++k) a3 += h2[k]*gw3[k*2 + t];
    out[N_NODES*2 + g*2 + t] = a3;
  }
}

extern "C" void kernel_launch(void* const* d_in, const int* in_sizes, int n_in,
                              void* d_out, int out_size, void* d_ws, size_t ws_size,
                              hipStream_t stream) {
  (void)in_sizes; (void)n_in; (void)out_size; (void)ws_size;
  const float* x       = (const float*)d_in[0];
  const int*   ei      = (const int*)d_in[1];
  const float* ea      = (const float*)d_in[2];
  const int*   batch   = (const int*)d_in[3];
  const float* W       = (const float*)d_in[4];
  const float* att_src = (const float*)d_in[5];
  const float* att_dst = (const float*)d_in[6];
  const float* We      = (const float*)d_in[7];
  const float* att_e   = (const float*)d_in[8];
  // d_in[9] = bias: cancels exactly in train-mode BN (and is zeros) -> unused
  const float* gamma   = (const float*)d_in[10];
  const float* beta    = (const float*)d_in[11];
  const float* nw1 = (const float*)d_in[12]; const float* nb1 = (const float*)d_in[13];
  const float* nw2 = (const float*)d_in[14]; const float* nb2 = (const float*)d_in[15];
  const float* nw3 = (const float*)d_in[16]; const float* nb3 = (const float*)d_in[17];
  const float* gw1 = (const float*)d_in[18]; const float* gb1 = (const float*)d_in[19];
  const float* gw2 = (const float*)d_in[20]; const float* gb2 = (const float*)d_in[21];
  const float* gw3 = (const float*)d_in[22]; const float* gb3 = (const float*)d_in[23];
  float* out = (float*)d_out;

  float* p = (float*)d_ws;
  float* xh    = p; p += (size_t)N_NODES*HC;     // 15.36M floats
  float* hbuf  = p; p += (size_t)N_NODES*HID;    // 3.84M
  float* hnext = p; p += (size_t)N_NODES*HID;    // 3.84M
  float* excsr = p; p += (size_t)N_EDGES*NH;     // 1.6M
  float* exself= p; p += (size_t)N_NODES*NH;     // 0.12M
  float* a_s   = p; p += (size_t)N_NODES*NH;
  float* a_d   = p; p += (size_t)N_NODES*NH;
  float* easum = p; p += (size_t)N_NODES*3;
  float* deg   = p; p += (size_t)N_NODES;
  float* wsrc  = p; p += NL*HID*NH;
  float* wdst  = p; p += NL*HID*NH;
  float* weatt = p; p += NL*3*NH;
  float* colsum= p; p += HID;
  float* colsq = p; p += HID;
  float* scale = p; p += HID;
  float* shift = p; p += HID;
  float* gsum  = p; p += NG*HID;
  float* gcnt  = p; p += NG;
  unsigned* gmaxenc = (unsigned*)p; p += NG*HID;
  int* rowptr  = (int*)p; p += (N_NODES + 1);
  int* fill    = (int*)p; p += N_NODES;
  int* csr_src = (int*)p; p += N_EDGES;
  int* csr_pos = (int*)p; p += N_EDGES;

  // once-per-call precompute
  hipMemsetAsync(easum, 0, (size_t)(N_NODES*3 + N_NODES)*sizeof(float), stream); // easum + deg
  prep_att_kernel<<<NL, 128, 0, stream>>>(W, att_src, att_dst, We, att_e, wsrc, wdst, weatt);
  deg_easum_kernel<<<(N_EDGES+255)/256, 256, 0, stream>>>(ei, ea, easum, deg);
  scan_kernel<<<1, 1024, 0, stream>>>(deg, rowptr, fill);
  csr_fill_kernel<<<(N_EDGES+255)/256, 256, 0, stream>>>(ei, rowptr, fill, csr_src, csr_pos);

  const float* hin = x;
  for (int l = 0; l < NL; ++l) {
    hipMemsetAsync(colsum, 0, 2*HID*sizeof(float), stream);  // colsum + colsq

    dim3 ggrid((N_NODES+63)/64, HC/64);
    gemm_xh_kernel<<<ggrid, 256, 0, stream>>>(hin, W + (size_t)l*HID*HC, xh);
    asd_kernel<<<(N_NODES*64)/256, 256, 0, stream>>>(hin, wsrc + l*HID*NH, wdst + l*HID*NH, a_s, a_d);
    edge_ex_kernel<<<(N_TOT+255)/256, 256, 0, stream>>>(ei, ea, easum, deg, a_s, a_d,
                                                        weatt + l*3*NH, csr_pos, excsr, exself);
    agg_kernel<<<(N_NODES*64+255)/256, 256, 0, stream>>>(rowptr, csr_src, excsr, exself, xh, hnext);
    bnstats_kernel<<<(N_NODES+63)/64, 256, 0, stream>>>(hnext, colsum, colsq);
    bnfin_kernel<<<1, 128, 0, stream>>>(colsum, colsq, gamma + l*HID, beta + l*HID, scale, shift);
    bnapply_kernel<<<(N_NODES*HID/4+255)/256, 256, 0, stream>>>(hnext, scale, shift, hbuf);
    hin = hbuf;
  }

  nodemlp_kernel<<<(N_NODES+255)/256, 256, 0, stream>>>(hbuf, nw1, nb1, nw2, nb2, nw3, nb3, out);

  hipMemsetAsync(gsum, 0, (size_t)(NG*HID + NG)*sizeof(float), stream);  // gsum + gcnt
  gmax_init_kernel<<<(NG*HID+255)/256, 256, 0, stream>>>(gmaxenc);
  pool_kernel<<<N_NODES, 128, 0, stream>>>(hbuf, batch, gsum, gmaxenc, gcnt);
  graphmlp_kernel<<<NG, 128, 0, stream>>>(gsum, gmaxenc, gcnt, gw1, gb1, gw2, gb2, gw3, gb3, out);
}

// Round 3
// 1126.201 us; speedup vs baseline: 1.9801x; 1.1535x over previous
//
#include <hip/hip_runtime.h>
#include <float.h>

#define N_NODES 30000
#define N_EDGES 400000
#define N_TOT   430000   // E + N self loops
#define HID     128
#define NH      4
#define HC      512      // NH * 128
#define NL      3
#define NG      64
#define NEG_SLOPE 0.2f
#define BN_EPS 1e-5f
#define POOL_CHUNK 256

__device__ __forceinline__ float atomAddF(float* p, float v) { return unsafeAtomicAdd(p, v); }

__device__ __forceinline__ unsigned encf(float x) {
  unsigned u = __float_as_uint(x);
  return (u & 0x80000000u) ? ~u : (u | 0x80000000u);
}
__device__ __forceinline__ float decf(unsigned u) {
  return (u & 0x80000000u) ? __uint_as_float(u ^ 0x80000000u) : __uint_as_float(~u);
}

// ---------------- attention projection precompute ----------------
__global__ void prep_att_kernel(const float* __restrict__ W, const float* __restrict__ att_src,
                                const float* __restrict__ att_dst, const float* __restrict__ We,
                                const float* __restrict__ att_e,
                                float* __restrict__ wsrc, float* __restrict__ wdst,
                                float* __restrict__ weatt) {
  int l = blockIdx.x, t = threadIdx.x;   // 128 threads
  for (int h = 0; h < NH; ++h) {
    const float* as = att_src + (size_t)(l*NH + h)*HID;
    const float* ad = att_dst + (size_t)(l*NH + h)*HID;
    const float* wr = W + (size_t)(l*HID + t)*HC + h*HID;
    float s = 0.f, d = 0.f;
    for (int c = 0; c < HID; ++c) { float w = wr[c]; s += w*as[c]; d += w*ad[c]; }
    wsrc[(l*HID + t)*NH + h] = s;
    wdst[(l*HID + t)*NH + h] = d;
  }
  if (t < 3) {
    for (int h = 0; h < NH; ++h) {
      const float* ae = att_e + (size_t)(l*NH + h)*HID;
      const float* wr = We + (size_t)(l*3 + t)*HC + h*HID;
      float s = 0.f;
      for (int c = 0; c < HID; ++c) s += wr[c]*ae[c];
      weatt[(l*3 + t)*NH + h] = s;
    }
  }
}

// in-degree and incoming-edge-attr sum (for self-loop fill_value='mean')
__global__ void deg_easum_kernel(const int* __restrict__ ei, const float* __restrict__ ea,
                                 float* __restrict__ easum, float* __restrict__ deg) {
  int e = blockIdx.x*blockDim.x + threadIdx.x;
  if (e >= N_EDGES) return;
  int d = ei[N_EDGES + e];
  atomAddF(&deg[d], 1.0f);
  atomAddF(&easum[d*3+0], ea[e*3+0]);
  atomAddF(&easum[d*3+1], ea[e*3+1]);
  atomAddF(&easum[d*3+2], ea[e*3+2]);
}

// ---------------- CSR build: rowptr = exclusive scan of deg ----------------
__global__ __launch_bounds__(1024) void scan_kernel(const float* __restrict__ deg,
                                                    int* __restrict__ rowptr,
                                                    int* __restrict__ fill) {
  __shared__ int part[1024];
  int t = threadIdx.x;
  const int CH = (N_NODES + 1023) / 1024;  // 30
  int base = t * CH;
  int s = 0;
  for (int i = 0; i < CH; ++i) {
    int n = base + i;
    if (n < N_NODES) s += (int)deg[n];
  }
  part[t] = s;
  __syncthreads();
  for (int off = 1; off < 1024; off <<= 1) {
    int v = (t >= off) ? part[t - off] : 0;
    __syncthreads();
    if (t >= off) part[t] += v;
    __syncthreads();
  }
  int prefix = (t == 0) ? 0 : part[t-1];
  for (int i = 0; i < CH; ++i) {
    int n = base + i;
    if (n < N_NODES) {
      rowptr[n] = prefix;
      fill[n] = 0;
      prefix += (int)deg[n];
    }
  }
  if (t == 1023) rowptr[N_NODES] = part[1023];
}

__global__ void csr_fill_kernel(const int* __restrict__ ei, const int* __restrict__ rowptr,
                                int* __restrict__ fill, int* __restrict__ csr_src,
                                int* __restrict__ csr_pos) {
  int e = blockIdx.x*blockDim.x + threadIdx.x;
  if (e >= N_EDGES) return;
  int s = ei[e], d = ei[N_EDGES + e];
  int pos = rowptr[d] + atomicAdd(&fill[d], 1);
  csr_src[pos] = s;
  csr_pos[e] = pos;
}

// ---------------- xh = h @ W[l] : [30000,128] x [128,512] ----------------
__global__ __launch_bounds__(256) void gemm_xh_kernel(const float* __restrict__ A,
                                                      const float* __restrict__ B,
                                                      float* __restrict__ C) {
  __shared__ float As[64][68];
  __shared__ float Bs[64][68];
  int m0 = blockIdx.x*64, n0 = blockIdx.y*64;
  int t = threadIdx.x, tx = t & 15, ty = t >> 4;
  float acc[4][4] = {};
  for (int kt = 0; kt < 2; ++kt) {
    #pragma unroll
    for (int i = 0; i < 16; ++i) {
      int idx = t + i*256;
      int m = idx >> 6, k = idx & 63;
      int gm = m0 + m;
      As[m][k] = (gm < N_NODES) ? A[(size_t)gm*HID + kt*64 + k] : 0.f;
      Bs[m][k] = B[(size_t)(kt*64 + m)*HC + n0 + k];
    }
    __syncthreads();
    #pragma unroll 8
    for (int k = 0; k < 64; ++k) {
      float a0 = As[ty][k];
      float a1 = As[ty+16][k];
      float a2 = As[ty+32][k];
      float a3 = As[ty+48][k];
      float4 bv = *(const float4*)&Bs[k][tx*4];
      acc[0][0] = fmaf(a0, bv.x, acc[0][0]); acc[0][1] = fmaf(a0, bv.y, acc[0][1]);
      acc[0][2] = fmaf(a0, bv.z, acc[0][2]); acc[0][3] = fmaf(a0, bv.w, acc[0][3]);
      acc[1][0] = fmaf(a1, bv.x, acc[1][0]); acc[1][1] = fmaf(a1, bv.y, acc[1][1]);
      acc[1][2] = fmaf(a1, bv.z, acc[1][2]); acc[1][3] = fmaf(a1, bv.w, acc[1][3]);
      acc[2][0] = fmaf(a2, bv.x, acc[2][0]); acc[2][1] = fmaf(a2, bv.y, acc[2][1]);
      acc[2][2] = fmaf(a2, bv.z, acc[2][2]); acc[2][3] = fmaf(a2, bv.w, acc[2][3]);
      acc[3][0] = fmaf(a3, bv.x, acc[3][0]); acc[3][1] = fmaf(a3, bv.y, acc[3][1]);
      acc[3][2] = fmaf(a3, bv.z, acc[3][2]); acc[3][3] = fmaf(a3, bv.w, acc[3][3]);
    }
    __syncthreads();
  }
  #pragma unroll
  for (int i = 0; i < 4; ++i) {
    int gm = m0 + ty + 16*i;
    if (gm < N_NODES)
      *(float4*)&C[(size_t)gm*HC + n0 + tx*4] =
          make_float4(acc[i][0], acc[i][1], acc[i][2], acc[i][3]);
  }
}

// ---------------- a_s/a_d : one wave per node ----------------
__global__ __launch_bounds__(256) void asd_kernel(const float* __restrict__ hin,
                                                  const float* __restrict__ wsrcL,
                                                  const float* __restrict__ wdstL,
                                                  float* __restrict__ a_s, float* __restrict__ a_d) {
  int wid = (blockIdx.x*256 + threadIdx.x) >> 6;
  int lane = threadIdx.x & 63;
  if (wid >= N_NODES) return;
  float v0 = hin[(size_t)wid*HID + lane];
  float v1 = hin[(size_t)wid*HID + 64 + lane];
  float4 w0s = *(const float4*)&wsrcL[lane*4];
  float4 w1s = *(const float4*)&wsrcL[(64+lane)*4];
  float4 w0d = *(const float4*)&wdstL[lane*4];
  float4 w1d = *(const float4*)&wdstL[(64+lane)*4];
  float ps0 = v0*w0s.x + v1*w1s.x, ps1 = v0*w0s.y + v1*w1s.y;
  float ps2 = v0*w0s.z + v1*w1s.z, ps3 = v0*w0s.w + v1*w1s.w;
  float pd0 = v0*w0d.x + v1*w1d.x, pd1 = v0*w0d.y + v1*w1d.y;
  float pd2 = v0*w0d.z + v1*w1d.z, pd3 = v0*w0d.w + v1*w1d.w;
  #pragma unroll
  for (int off = 32; off > 0; off >>= 1) {
    ps0 += __shfl_xor(ps0, off); ps1 += __shfl_xor(ps1, off);
    ps2 += __shfl_xor(ps2, off); ps3 += __shfl_xor(ps3, off);
    pd0 += __shfl_xor(pd0, off); pd1 += __shfl_xor(pd1, off);
    pd2 += __shfl_xor(pd2, off); pd3 += __shfl_xor(pd3, off);
  }
  if (lane == 0) {
    *(float4*)&a_s[wid*4] = make_float4(ps0, ps1, ps2, ps3);
    *(float4*)&a_d[wid*4] = make_float4(pd0, pd1, pd2, pd3);
  }
}

// ---------------- edge pass: ex = exp(leakyrelu(...)) written in CSR order ----------------
__global__ void edge_ex_kernel(const int* __restrict__ ei, const float* __restrict__ ea,
                               const float* __restrict__ easum, const float* __restrict__ deg,
                               const float* __restrict__ a_s, const float* __restrict__ a_d,
                               const float* __restrict__ weattL, const int* __restrict__ csr_pos,
                               float* __restrict__ excsr, float* __restrict__ exself) {
  int e = blockIdx.x*blockDim.x + threadIdx.x;
  if (e >= N_TOT) return;
  int s, d; float e0, e1, e2;
  if (e < N_EDGES) {
    s = ei[e]; d = ei[N_EDGES + e];
    e0 = ea[e*3+0]; e1 = ea[e*3+1]; e2 = ea[e*3+2];
  } else {
    int n = e - N_EDGES; s = n; d = n;
    float inv = 1.f / fmaxf(deg[n], 1.f);
    e0 = easum[n*3+0]*inv; e1 = easum[n*3+1]*inv; e2 = easum[n*3+2]*inv;
  }
  float4 as4 = *(const float4*)&a_s[s*4];
  float4 ad4 = *(const float4*)&a_d[d*4];
  float4 w0 = *(const float4*)&weattL[0];
  float4 w1 = *(const float4*)&weattL[4];
  float4 w2 = *(const float4*)&weattL[8];
  float raw0 = as4.x + ad4.x + e0*w0.x + e1*w1.x + e2*w2.x;
  float raw1 = as4.y + ad4.y + e0*w0.y + e1*w1.y + e2*w2.y;
  float raw2 = as4.z + ad4.z + e0*w0.z + e1*w1.z + e2*w2.z;
  float raw3 = as4.w + ad4.w + e0*w0.w + e1*w1.w + e2*w2.w;
  raw0 = raw0 > 0.f ? raw0 : NEG_SLOPE*raw0;
  raw1 = raw1 > 0.f ? raw1 : NEG_SLOPE*raw1;
  raw2 = raw2 > 0.f ? raw2 : NEG_SLOPE*raw2;
  raw3 = raw3 > 0.f ? raw3 : NEG_SLOPE*raw3;
  float4 exv = make_float4(__expf(raw0), __expf(raw1), __expf(raw2), __expf(raw3));
  if (e < N_EDGES) {
    *(float4*)&excsr[(size_t)csr_pos[e]*4] = exv;
  } else {
    *(float4*)&exself[(size_t)(e - N_EDGES)*4] = exv;
  }
}

// ---------------- CSR aggregation: one wave per dst node, no atomics ----------------
__global__ __launch_bounds__(256) void agg_kernel(const int* __restrict__ rowptr,
    const int* __restrict__ csr_src, const float* __restrict__ excsr,
    const float* __restrict__ exself, const float* __restrict__ xh,
    float* __restrict__ hnext) {
  int wid = (blockIdx.x*256 + threadIdx.x) >> 6;   // dst node id
  int lane = threadIdx.x & 63;
  if (wid >= N_NODES) return;
  int p0 = rowptr[wid], p1 = rowptr[wid+1];
  int cc = lane*2;
  float a00, a01, a10, a11, a20, a21, a30, a31;
  float den0, den1, den2, den3;
  {
    float4 exv = *(const float4*)&exself[(size_t)wid*4];
    den0 = exv.x; den1 = exv.y; den2 = exv.z; den3 = exv.w;
    const float* xr = xh + (size_t)wid*HC + cc;
    float2 v0 = *(const float2*)&xr[0];
    float2 v1 = *(const float2*)&xr[128];
    float2 v2 = *(const float2*)&xr[256];
    float2 v3 = *(const float2*)&xr[384];
    a00 = exv.x*v0.x; a01 = exv.x*v0.y;
    a10 = exv.y*v1.x; a11 = exv.y*v1.y;
    a20 = exv.z*v2.x; a21 = exv.z*v2.y;
    a30 = exv.w*v3.x; a31 = exv.w*v3.y;
  }
  for (int p = p0; p < p1; ++p) {
    int s = csr_src[p];
    float4 exv = *(const float4*)&excsr[(size_t)p*4];
    den0 += exv.x; den1 += exv.y; den2 += exv.z; den3 += exv.w;
    const float* xr = xh + (size_t)s*HC + cc;
    float2 v0 = *(const float2*)&xr[0];
    float2 v1 = *(const float2*)&xr[128];
    float2 v2 = *(const float2*)&xr[256];
    float2 v3 = *(const float2*)&xr[384];
    a00 = fmaf(exv.x, v0.x, a00); a01 = fmaf(exv.x, v0.y, a01);
    a10 = fmaf(exv.y, v1.x, a10); a11 = fmaf(exv.y, v1.y, a11);
    a20 = fmaf(exv.z, v2.x, a20); a21 = fmaf(exv.z, v2.y, a21);
    a30 = fmaf(exv.w, v3.x, a30); a31 = fmaf(exv.w, v3.y, a31);
  }
  float i0 = 1.f/den0, i1 = 1.f/den1, i2 = 1.f/den2, i3 = 1.f/den3;
  float x0 = 0.25f*(a00*i0 + a10*i1 + a20*i2 + a30*i3);
  float x1 = 0.25f*(a01*i0 + a11*i1 + a21*i2 + a31*i3);
  *(float2*)&hnext[(size_t)wid*HID + cc] = make_float2(x0, x1);
}

// ---------------- BatchNorm: column sums / sumsq ----------------
__global__ void bnstats_kernel(const float* __restrict__ hpre,
                               float* __restrict__ colsum, float* __restrict__ colsq) {
  __shared__ float ssum[256], ssq[256];
  int t = threadIdx.x;
  int c = t & 127, half = t >> 7;
  int r0 = blockIdx.x * 64;
  float s = 0.f, q = 0.f;
  for (int j = half; j < 64; j += 2) {
    int r = r0 + j;
    if (r < N_NODES) { float v = hpre[(size_t)r*HID + c]; s += v; q += v*v; }
  }
  ssum[t] = s; ssq[t] = q;
  __syncthreads();
  if (half == 0) {
    atomAddF(&colsum[c], ssum[c] + ssum[c+128]);
    atomAddF(&colsq[c],  ssq[c]  + ssq[c+128]);
  }
}

__global__ void bnfin_kernel(const float* __restrict__ colsum, const float* __restrict__ colsq,
                             const float* __restrict__ gammaL, const float* __restrict__ betaL,
                             float* __restrict__ scale, float* __restrict__ shift) {
  int c = threadIdx.x;
  const float invn = 1.f / (float)N_NODES;
  float mu = colsum[c] * invn;
  float var = fmaxf(colsq[c]*invn - mu*mu, 0.f);
  float sc = gammaL[c] * rsqrtf(var + BN_EPS);
  scale[c] = sc;
  shift[c] = betaL[c] - mu*sc;
}

__global__ void bnapply_kernel(const float* __restrict__ hpre, const float* __restrict__ scale,
                               const float* __restrict__ shift, float* __restrict__ hout) {
  int i = blockIdx.x*blockDim.x + threadIdx.x;      // one float4 per thread
  if (i >= N_NODES*HID/4) return;
  int c4 = (i*4) & 127;
  float4 v = *(const float4*)&hpre[(size_t)i*4];
  float4 sc = *(const float4*)&scale[c4];
  float4 sh = *(const float4*)&shift[c4];
  v.x = fmaxf(fmaf(v.x, sc.x, sh.x), 0.f);
  v.y = fmaxf(fmaf(v.y, sc.y, sh.y), 0.f);
  v.z = fmaxf(fmaf(v.z, sc.z, sh.z), 0.f);
  v.w = fmaxf(fmaf(v.w, sc.w, sh.w), 0.f);
  *(float4*)&hout[(size_t)i*4] = v;
}

// ---------------- node MLP 128->64->32->2 (thread per node) ----------------
__global__ __launch_bounds__(256) void nodemlp_kernel(const float* __restrict__ h,
    const float* __restrict__ w1, const float* __restrict__ b1,
    const float* __restrict__ w2, const float* __restrict__ b2,
    const float* __restrict__ w3, const float* __restrict__ b3,
    float* __restrict__ out) {
  int n = blockIdx.x*256 + threadIdx.x;
  if (n >= N_NODES) return;
  const float* hr = h + (size_t)n*HID;
  float l1[64];
  #pragma unroll
  for (int o = 0; o < 64; ++o) l1[o] = b1[o];
  for (int k4 = 0; k4 < 32; ++k4) {
    float4 hv = *(const float4*)(hr + k4*4);
    const float* wp = &w1[k4*4*64];
    #pragma unroll
    for (int o = 0; o < 64; ++o)
      l1[o] += hv.x*wp[o] + hv.y*wp[64+o] + hv.z*wp[128+o] + hv.w*wp[192+o];
  }
  #pragma unroll
  for (int o = 0; o < 64; ++o) l1[o] = fmaxf(l1[o], 0.f);
  float l2[32];
  #pragma unroll
  for (int o = 0; o < 32; ++o) l2[o] = b2[o];
  for (int k = 0; k < 64; ++k) {
    float hv = l1[k];
    const float* wp = &w2[k*32];
    #pragma unroll
    for (int o = 0; o < 32; ++o) l2[o] += hv*wp[o];
  }
  float o0 = b3[0], o1 = b3[1];
  #pragma unroll
  for (int k = 0; k < 32; ++k) {
    float hv = fmaxf(l2[k], 0.f);
    o0 += hv*w3[k*2]; o1 += hv*w3[k*2+1];
  }
  out[(size_t)n*2]   = o0;
  out[(size_t)n*2+1] = o1;
}

// ---------------- graph pooling (segmented over sorted batch) ----------------
__global__ void gmax_init_kernel(unsigned* __restrict__ gmaxenc) {
  int i = blockIdx.x*blockDim.x + threadIdx.x;
  if (i < NG*HID) gmaxenc[i] = 0x00800000u;   // enc(-FLT_MAX)
}

__global__ __launch_bounds__(128) void pool_seg_kernel(const float* __restrict__ h,
                                                       const int* __restrict__ batch,
                                                       float* __restrict__ gsum,
                                                       unsigned* __restrict__ gmaxenc,
                                                       float* __restrict__ gcnt) {
  int t = threadIdx.x;                       // column
  int r0 = blockIdx.x * POOL_CHUNK;
  int rend = min(r0 + POOL_CHUNK, N_NODES);
  if (r0 >= N_NODES) return;
  int gcur = batch[r0];
  float s = 0.f, m = -FLT_MAX;
  int cnt = 0;
  for (int r = r0; r < rend; ++r) {
    int g = batch[r];                        // wave-uniform scalar load
    if (g != gcur) {
      atomAddF(&gsum[gcur*HID + t], s);
      atomicMax(&gmaxenc[gcur*HID + t], encf(m));
      if (t == 0) atomAddF(&gcnt[gcur], (float)cnt);
      gcur = g; s = 0.f; m = -FLT_MAX; cnt = 0;
    }
    float v = h[(size_t)r*HID + t];
    s += v; m = fmaxf(m, v);
    ++cnt;
  }
  atomAddF(&gsum[gcur*HID + t], s);
  atomicMax(&gmaxenc[gcur*HID + t], encf(m));
  if (t == 0) atomAddF(&gcnt[gcur], (float)cnt);
}

// ---------------- graph MLP 256->128->64->2 (block per graph) ----------------
__global__ __launch_bounds__(128) void graphmlp_kernel(const float* __restrict__ gsum,
    const unsigned* __restrict__ gmaxenc, const float* __restrict__ gcnt,
    const float* __restrict__ gw1, const float* __restrict__ gb1,
    const float* __restrict__ gw2, const float* __restrict__ gb2,
    const float* __restrict__ gw3, const float* __restrict__ gb3,
    float* __restrict__ out) {
  __shared__ float gr[256], h1[128], h2[64];
  int g = blockIdx.x, t = threadIdx.x;
  float cnt = fmaxf(gcnt[g], 1.f);
  gr[t] = gsum[g*HID + t] / cnt;
  gr[128 + t] = decf(gmaxenc[g*HID + t]);
  __syncthreads();
  float acc = gb1[t];
  for (int k = 0; k < 256; ++k) acc += gr[k]*gw1[k*HID + t];
  h1[t] = fmaxf(acc, 0.f);
  __syncthreads();
  if (t < 64) {
    float a2 = gb2[t];
    for (int k = 0; k < 128; ++k) a2 += h1[k]*gw2[k*64 + t];
    h2[t] = fmaxf(a2, 0.f);
  }
  __syncthreads();
  if (t < 2) {
    float a3 = gb3[t];
    for (int k = 0; k < 64; ++k) a3 += h2[k]*gw3[k*2 + t];
    out[N_NODES*2 + g*2 + t] = a3;
  }
}

extern "C" void kernel_launch(void* const* d_in, const int* in_sizes, int n_in,
                              void* d_out, int out_size, void* d_ws, size_t ws_size,
                              hipStream_t stream) {
  (void)in_sizes; (void)n_in; (void)out_size; (void)ws_size;
  const float* x       = (const float*)d_in[0];
  const int*   ei      = (const int*)d_in[1];
  const float* ea      = (const float*)d_in[2];
  const int*   batch   = (const int*)d_in[3];
  const float* W       = (const float*)d_in[4];
  const float* att_src = (const float*)d_in[5];
  const float* att_dst = (const float*)d_in[6];
  const float* We      = (const float*)d_in[7];
  const float* att_e   = (const float*)d_in[8];
  // d_in[9] = bias: cancels exactly in train-mode BN (and is zeros) -> unused
  const float* gamma   = (const float*)d_in[10];
  const float* beta    = (const float*)d_in[11];
  const float* nw1 = (const float*)d_in[12]; const float* nb1 = (const float*)d_in[13];
  const float* nw2 = (const float*)d_in[14]; const float* nb2 = (const float*)d_in[15];
  const float* nw3 = (const float*)d_in[16]; const float* nb3 = (const float*)d_in[17];
  const float* gw1 = (const float*)d_in[18]; const float* gb1 = (const float*)d_in[19];
  const float* gw2 = (const float*)d_in[20]; const float* gb2 = (const float*)d_in[21];
  const float* gw3 = (const float*)d_in[22]; const float* gb3 = (const float*)d_in[23];
  float* out = (float*)d_out;

  float* p = (float*)d_ws;
  float* xh    = p; p += (size_t)N_NODES*HC;     // 15.36M floats
  float* hbuf  = p; p += (size_t)N_NODES*HID;    // 3.84M
  float* hnext = p; p += (size_t)N_NODES*HID;    // 3.84M
  float* excsr = p; p += (size_t)N_EDGES*NH;     // 1.6M
  float* exself= p; p += (size_t)N_NODES*NH;     // 0.12M
  float* a_s   = p; p += (size_t)N_NODES*NH;
  float* a_d   = p; p += (size_t)N_NODES*NH;
  float* easum = p; p += (size_t)N_NODES*3;
  float* deg   = p; p += (size_t)N_NODES;
  float* wsrc  = p; p += NL*HID*NH;
  float* wdst  = p; p += NL*HID*NH;
  float* weatt = p; p += NL*3*NH;
  float* colsum= p; p += HID;
  float* colsq = p; p += HID;
  float* scale = p; p += HID;
  float* shift = p; p += HID;
  float* gsum  = p; p += NG*HID;
  float* gcnt  = p; p += NG;
  unsigned* gmaxenc = (unsigned*)p; p += NG*HID;
  int* rowptr  = (int*)p; p += (N_NODES + 1);
  int* fill    = (int*)p; p += N_NODES;
  int* csr_src = (int*)p; p += N_EDGES;
  int* csr_pos = (int*)p; p += N_EDGES;

  // once-per-call precompute
  hipMemsetAsync(easum, 0, (size_t)(N_NODES*3 + N_NODES)*sizeof(float), stream); // easum + deg
  prep_att_kernel<<<NL, 128, 0, stream>>>(W, att_src, att_dst, We, att_e, wsrc, wdst, weatt);
  deg_easum_kernel<<<(N_EDGES+255)/256, 256, 0, stream>>>(ei, ea, easum, deg);
  scan_kernel<<<1, 1024, 0, stream>>>(deg, rowptr, fill);
  csr_fill_kernel<<<(N_EDGES+255)/256, 256, 0, stream>>>(ei, rowptr, fill, csr_src, csr_pos);

  const float* hin = x;
  for (int l = 0; l < NL; ++l) {
    hipMemsetAsync(colsum, 0, 2*HID*sizeof(float), stream);  // colsum + colsq

    dim3 ggrid((N_NODES+63)/64, HC/64);
    gemm_xh_kernel<<<ggrid, 256, 0, stream>>>(hin, W + (size_t)l*HID*HC, xh);
    asd_kernel<<<(N_NODES*64)/256, 256, 0, stream>>>(hin, wsrc + l*HID*NH, wdst + l*HID*NH, a_s, a_d);
    edge_ex_kernel<<<(N_TOT+255)/256, 256, 0, stream>>>(ei, ea, easum, deg, a_s, a_d,
                                                        weatt + l*3*NH, csr_pos, excsr, exself);
    agg_kernel<<<(N_NODES*64+255)/256, 256, 0, stream>>>(rowptr, csr_src, excsr, exself, xh, hnext);
    bnstats_kernel<<<(N_NODES+63)/64, 256, 0, stream>>>(hnext, colsum, colsq);
    bnfin_kernel<<<1, 128, 0, stream>>>(colsum, colsq, gamma + l*HID, beta + l*HID, scale, shift);
    bnapply_kernel<<<(N_NODES*HID/4+255)/256, 256, 0, stream>>>(hnext, scale, shift, hbuf);
    hin = hbuf;
  }

  nodemlp_kernel<<<(N_NODES+255)/256, 256, 0, stream>>>(hbuf, nw1, nb1, nw2, nb2, nw3, nb3, out);

  hipMemsetAsync(gsum, 0, (size_t)(NG*HID + NG)*sizeof(float), stream);  // gsum + gcnt
  gmax_init_kernel<<<(NG*HID+255)/256, 256, 0, stream>>>(gmaxenc);
  pool_seg_kernel<<<(N_NODES + POOL_CHUNK - 1)/POOL_CHUNK, 128, 0, stream>>>(hbuf, batch, gsum, gmaxenc, gcnt);
  graphmlp_kernel<<<NG, 128, 0, stream>>>(gsum, gmaxenc, gcnt, gw1, gb1, gw2, gb2, gw3, gb3, out);
}

// Round 4
// 981.409 us; speedup vs baseline: 2.2722x; 1.1475x over previous
//
#include <hip/hip_runtime.h>
#include <float.h>

#define N_NODES 30000
#define N_EDGES 400000
#define N_TOT   430000   // E + N self loops
#define HID     128
#define NH      4
#define HC      512      // NH * 128
#define NL      3
#define NG      64
#define NEG_SLOPE 0.2f
#define BN_EPS 1e-5f
#define POOL_CHUNK 256

__device__ __forceinline__ float atomAddF(float* p, float v) { return unsafeAtomicAdd(p, v); }

__device__ __forceinline__ unsigned encf(float x) {
  unsigned u = __float_as_uint(x);
  return (u & 0x80000000u) ? ~u : (u | 0x80000000u);
}
__device__ __forceinline__ float decf(unsigned u) {
  return (u & 0x80000000u) ? __uint_as_float(u ^ 0x80000000u) : __uint_as_float(~u);
}
__device__ __forceinline__ unsigned short f2bf(float f) {   // RNE
  unsigned u = __float_as_uint(f);
  u += 0x7FFFu + ((u >> 16) & 1u);
  return (unsigned short)(u >> 16);
}
__device__ __forceinline__ float bf2f(unsigned short s) {
  return __uint_as_float(((unsigned)s) << 16);
}

// ---------------- attention projection precompute ----------------
__global__ void prep_att_kernel(const float* __restrict__ W, const float* __restrict__ att_src,
                                const float* __restrict__ att_dst, const float* __restrict__ We,
                                const float* __restrict__ att_e,
                                float* __restrict__ wsrc, float* __restrict__ wdst,
                                float* __restrict__ weatt) {
  int l = blockIdx.x, t = threadIdx.x;   // 128 threads
  for (int h = 0; h < NH; ++h) {
    const float* as = att_src + (size_t)(l*NH + h)*HID;
    const float* ad = att_dst + (size_t)(l*NH + h)*HID;
    const float* wr = W + (size_t)(l*HID + t)*HC + h*HID;
    float s = 0.f, d = 0.f;
    for (int c = 0; c < HID; ++c) { float w = wr[c]; s += w*as[c]; d += w*ad[c]; }
    wsrc[(l*HID + t)*NH + h] = s;
    wdst[(l*HID + t)*NH + h] = d;
  }
  if (t < 3) {
    for (int h = 0; h < NH; ++h) {
      const float* ae = att_e + (size_t)(l*NH + h)*HID;
      const float* wr = We + (size_t)(l*3 + t)*HC + h*HID;
      float s = 0.f;
      for (int c = 0; c < HID; ++c) s += wr[c]*ae[c];
      weatt[(l*3 + t)*NH + h] = s;
    }
  }
}

// in-degree and incoming-edge-attr sum (for self-loop fill_value='mean')
__global__ void deg_easum_kernel(const int* __restrict__ ei, const float* __restrict__ ea,
                                 float* __restrict__ easum, float* __restrict__ deg) {
  int e = blockIdx.x*blockDim.x + threadIdx.x;
  if (e >= N_EDGES) return;
  int d = ei[N_EDGES + e];
  atomAddF(&deg[d], 1.0f);
  atomAddF(&easum[d*3+0], ea[e*3+0]);
  atomAddF(&easum[d*3+1], ea[e*3+1]);
  atomAddF(&easum[d*3+2], ea[e*3+2]);
}

// ---------------- CSR build: rowptr = exclusive scan of deg ----------------
__global__ __launch_bounds__(1024) void scan_kernel(const float* __restrict__ deg,
                                                    int* __restrict__ rowptr,
                                                    int* __restrict__ fill) {
  __shared__ int part[1024];
  int t = threadIdx.x;
  const int CH = (N_NODES + 1023) / 1024;  // 30
  int base = t * CH;
  int s = 0;
  for (int i = 0; i < CH; ++i) {
    int n = base + i;
    if (n < N_NODES) s += (int)deg[n];
  }
  part[t] = s;
  __syncthreads();
  for (int off = 1; off < 1024; off <<= 1) {
    int v = (t >= off) ? part[t - off] : 0;
    __syncthreads();
    if (t >= off) part[t] += v;
    __syncthreads();
  }
  int prefix = (t == 0) ? 0 : part[t-1];
  for (int i = 0; i < CH; ++i) {
    int n = base + i;
    if (n < N_NODES) {
      rowptr[n] = prefix;
      fill[n] = 0;
      prefix += (int)deg[n];
    }
  }
  if (t == 1023) rowptr[N_NODES] = part[1023];
}

__global__ void csr_fill_kernel(const int* __restrict__ ei, const int* __restrict__ rowptr,
                                int* __restrict__ fill, int* __restrict__ csr_src,
                                int* __restrict__ csr_pos) {
  int e = blockIdx.x*blockDim.x + threadIdx.x;
  if (e >= N_EDGES) return;
  int s = ei[e], d = ei[N_EDGES + e];
  int pos = rowptr[d] + atomicAdd(&fill[d], 1);
  csr_src[pos] = s;
  csr_pos[e] = pos;
}

// ---------------- xh = h @ W[l] : [30000,128] x [128,512], bf16 output ----------------
__global__ __launch_bounds__(256) void gemm_xh_kernel(const float* __restrict__ A,
                                                      const float* __restrict__ B,
                                                      unsigned short* __restrict__ C) {
  __shared__ float As[64][68];
  __shared__ float Bs[64][68];
  int m0 = blockIdx.x*64, n0 = blockIdx.y*64;
  int t = threadIdx.x, tx = t & 15, ty = t >> 4;
  float acc[4][4] = {};
  for (int kt = 0; kt < 2; ++kt) {
    #pragma unroll
    for (int i = 0; i < 16; ++i) {
      int idx = t + i*256;
      int m = idx >> 6, k = idx & 63;
      int gm = m0 + m;
      As[m][k] = (gm < N_NODES) ? A[(size_t)gm*HID + kt*64 + k] : 0.f;
      Bs[m][k] = B[(size_t)(kt*64 + m)*HC + n0 + k];
    }
    __syncthreads();
    #pragma unroll 8
    for (int k = 0; k < 64; ++k) {
      float a0 = As[ty][k];
      float a1 = As[ty+16][k];
      float a2 = As[ty+32][k];
      float a3 = As[ty+48][k];
      float4 bv = *(const float4*)&Bs[k][tx*4];
      acc[0][0] = fmaf(a0, bv.x, acc[0][0]); acc[0][1] = fmaf(a0, bv.y, acc[0][1]);
      acc[0][2] = fmaf(a0, bv.z, acc[0][2]); acc[0][3] = fmaf(a0, bv.w, acc[0][3]);
      acc[1][0] = fmaf(a1, bv.x, acc[1][0]); acc[1][1] = fmaf(a1, bv.y, acc[1][1]);
      acc[1][2] = fmaf(a1, bv.z, acc[1][2]); acc[1][3] = fmaf(a1, bv.w, acc[1][3]);
      acc[2][0] = fmaf(a2, bv.x, acc[2][0]); acc[2][1] = fmaf(a2, bv.y, acc[2][1]);
      acc[2][2] = fmaf(a2, bv.z, acc[2][2]); acc[2][3] = fmaf(a2, bv.w, acc[2][3]);
      acc[3][0] = fmaf(a3, bv.x, acc[3][0]); acc[3][1] = fmaf(a3, bv.y, acc[3][1]);
      acc[3][2] = fmaf(a3, bv.z, acc[3][2]); acc[3][3] = fmaf(a3, bv.w, acc[3][3]);
    }
    __syncthreads();
  }
  #pragma unroll
  for (int i = 0; i < 4; ++i) {
    int gm = m0 + ty + 16*i;
    if (gm < N_NODES) {
      ushort4 o;
      o.x = f2bf(acc[i][0]); o.y = f2bf(acc[i][1]);
      o.z = f2bf(acc[i][2]); o.w = f2bf(acc[i][3]);
      *(ushort4*)&C[(size_t)gm*HC + n0 + tx*4] = o;
    }
  }
}

// ---------------- a_s/a_d : one wave per node ----------------
__global__ __launch_bounds__(256) void asd_kernel(const float* __restrict__ hin,
                                                  const float* __restrict__ wsrcL,
                                                  const float* __restrict__ wdstL,
                                                  float* __restrict__ a_s, float* __restrict__ a_d) {
  int wid = (blockIdx.x*256 + threadIdx.x) >> 6;
  int lane = threadIdx.x & 63;
  if (wid >= N_NODES) return;
  float v0 = hin[(size_t)wid*HID + lane];
  float v1 = hin[(size_t)wid*HID + 64 + lane];
  float4 w0s = *(const float4*)&wsrcL[lane*4];
  float4 w1s = *(const float4*)&wsrcL[(64+lane)*4];
  float4 w0d = *(const float4*)&wdstL[lane*4];
  float4 w1d = *(const float4*)&wdstL[(64+lane)*4];
  float ps0 = v0*w0s.x + v1*w1s.x, ps1 = v0*w0s.y + v1*w1s.y;
  float ps2 = v0*w0s.z + v1*w1s.z, ps3 = v0*w0s.w + v1*w1s.w;
  float pd0 = v0*w0d.x + v1*w1d.x, pd1 = v0*w0d.y + v1*w1d.y;
  float pd2 = v0*w0d.z + v1*w1d.z, pd3 = v0*w0d.w + v1*w1d.w;
  #pragma unroll
  for (int off = 32; off > 0; off >>= 1) {
    ps0 += __shfl_xor(ps0, off); ps1 += __shfl_xor(ps1, off);
    ps2 += __shfl_xor(ps2, off); ps3 += __shfl_xor(ps3, off);
    pd0 += __shfl_xor(pd0, off); pd1 += __shfl_xor(pd1, off);
    pd2 += __shfl_xor(pd2, off); pd3 += __shfl_xor(pd3, off);
  }
  if (lane == 0) {
    *(float4*)&a_s[wid*4] = make_float4(ps0, ps1, ps2, ps3);
    *(float4*)&a_d[wid*4] = make_float4(pd0, pd1, pd2, pd3);
  }
}

// ---------------- edge pass: ex = exp(leakyrelu(...)) written in CSR order ----------------
__global__ void edge_ex_kernel(const int* __restrict__ ei, const float* __restrict__ ea,
                               const float* __restrict__ easum, const float* __restrict__ deg,
                               const float* __restrict__ a_s, const float* __restrict__ a_d,
                               const float* __restrict__ weattL, const int* __restrict__ csr_pos,
                               float* __restrict__ excsr, float* __restrict__ exself) {
  int e = blockIdx.x*blockDim.x + threadIdx.x;
  if (e >= N_TOT) return;
  int s, d; float e0, e1, e2;
  if (e < N_EDGES) {
    s = ei[e]; d = ei[N_EDGES + e];
    e0 = ea[e*3+0]; e1 = ea[e*3+1]; e2 = ea[e*3+2];
  } else {
    int n = e - N_EDGES; s = n; d = n;
    float inv = 1.f / fmaxf(deg[n], 1.f);
    e0 = easum[n*3+0]*inv; e1 = easum[n*3+1]*inv; e2 = easum[n*3+2]*inv;
  }
  float4 as4 = *(const float4*)&a_s[s*4];
  float4 ad4 = *(const float4*)&a_d[d*4];
  float4 w0 = *(const float4*)&weattL[0];
  float4 w1 = *(const float4*)&weattL[4];
  float4 w2 = *(const float4*)&weattL[8];
  float raw0 = as4.x + ad4.x + e0*w0.x + e1*w1.x + e2*w2.x;
  float raw1 = as4.y + ad4.y + e0*w0.y + e1*w1.y + e2*w2.y;
  float raw2 = as4.z + ad4.z + e0*w0.z + e1*w1.z + e2*w2.z;
  float raw3 = as4.w + ad4.w + e0*w0.w + e1*w1.w + e2*w2.w;
  raw0 = raw0 > 0.f ? raw0 : NEG_SLOPE*raw0;
  raw1 = raw1 > 0.f ? raw1 : NEG_SLOPE*raw1;
  raw2 = raw2 > 0.f ? raw2 : NEG_SLOPE*raw2;
  raw3 = raw3 > 0.f ? raw3 : NEG_SLOPE*raw3;
  float4 exv = make_float4(__expf(raw0), __expf(raw1), __expf(raw2), __expf(raw3));
  if (e < N_EDGES) {
    *(float4*)&excsr[(size_t)csr_pos[e]*4] = exv;
  } else {
    *(float4*)&exself[(size_t)(e - N_EDGES)*4] = exv;
  }
}

// ---------------- CSR aggregation: one wave per dst node, bf16 xh gather ----------------
__global__ __launch_bounds__(256) void agg_kernel(const int* __restrict__ rowptr,
    const int* __restrict__ csr_src, const float* __restrict__ excsr,
    const float* __restrict__ exself, const unsigned short* __restrict__ xh,
    float* __restrict__ hnext) {
  int wid = (blockIdx.x*256 + threadIdx.x) >> 6;   // dst node id
  int lane = threadIdx.x & 63;
  if (wid >= N_NODES) return;
  int p0 = rowptr[wid], p1 = rowptr[wid+1];
  int cc = lane*2;
  float a00, a01, a10, a11, a20, a21, a30, a31;
  float den0, den1, den2, den3;
  {
    float4 exv = *(const float4*)&exself[(size_t)wid*4];
    den0 = exv.x; den1 = exv.y; den2 = exv.z; den3 = exv.w;
    const unsigned short* xr = xh + (size_t)wid*HC + cc;
    ushort2 r0 = *(const ushort2*)&xr[0];
    ushort2 r1 = *(const ushort2*)&xr[128];
    ushort2 r2 = *(const ushort2*)&xr[256];
    ushort2 r3 = *(const ushort2*)&xr[384];
    a00 = exv.x*bf2f(r0.x); a01 = exv.x*bf2f(r0.y);
    a10 = exv.y*bf2f(r1.x); a11 = exv.y*bf2f(r1.y);
    a20 = exv.z*bf2f(r2.x); a21 = exv.z*bf2f(r2.y);
    a30 = exv.w*bf2f(r3.x); a31 = exv.w*bf2f(r3.y);
  }
  for (int p = p0; p < p1; ++p) {
    int s = csr_src[p];
    float4 exv = *(const float4*)&excsr[(size_t)p*4];
    den0 += exv.x; den1 += exv.y; den2 += exv.z; den3 += exv.w;
    const unsigned short* xr = xh + (size_t)s*HC + cc;
    ushort2 r0 = *(const ushort2*)&xr[0];
    ushort2 r1 = *(const ushort2*)&xr[128];
    ushort2 r2 = *(const ushort2*)&xr[256];
    ushort2 r3 = *(const ushort2*)&xr[384];
    a00 = fmaf(exv.x, bf2f(r0.x), a00); a01 = fmaf(exv.x, bf2f(r0.y), a01);
    a10 = fmaf(exv.y, bf2f(r1.x), a10); a11 = fmaf(exv.y, bf2f(r1.y), a11);
    a20 = fmaf(exv.z, bf2f(r2.x), a20); a21 = fmaf(exv.z, bf2f(r2.y), a21);
    a30 = fmaf(exv.w, bf2f(r3.x), a30); a31 = fmaf(exv.w, bf2f(r3.y), a31);
  }
  float i0 = 1.f/den0, i1 = 1.f/den1, i2 = 1.f/den2, i3 = 1.f/den3;
  float x0 = 0.25f*(a00*i0 + a10*i1 + a20*i2 + a30*i3);
  float x1 = 0.25f*(a01*i0 + a11*i1 + a21*i2 + a31*i3);
  *(float2*)&hnext[(size_t)wid*HID + cc] = make_float2(x0, x1);
}

// ---------------- BatchNorm: column sums / sumsq ----------------
__global__ void bnstats_kernel(const float* __restrict__ hpre,
                               float* __restrict__ colsum, float* __restrict__ colsq) {
  __shared__ float ssum[256], ssq[256];
  int t = threadIdx.x;
  int c = t & 127, half = t >> 7;
  int r0 = blockIdx.x * 64;
  float s = 0.f, q = 0.f;
  for (int j = half; j < 64; j += 2) {
    int r = r0 + j;
    if (r < N_NODES) { float v = hpre[(size_t)r*HID + c]; s += v; q += v*v; }
  }
  ssum[t] = s; ssq[t] = q;
  __syncthreads();
  if (half == 0) {
    atomAddF(&colsum[c], ssum[c] + ssum[c+128]);
    atomAddF(&colsq[c],  ssq[c]  + ssq[c+128]);
  }
}

__global__ void bnfin_kernel(const float* __restrict__ colsum, const float* __restrict__ colsq,
                             const float* __restrict__ gammaL, const float* __restrict__ betaL,
                             float* __restrict__ scale, float* __restrict__ shift) {
  int c = threadIdx.x;
  const float invn = 1.f / (float)N_NODES;
  float mu = colsum[c] * invn;
  float var = fmaxf(colsq[c]*invn - mu*mu, 0.f);
  float sc = gammaL[c] * rsqrtf(var + BN_EPS);
  scale[c] = sc;
  shift[c] = betaL[c] - mu*sc;
}

__global__ void bnapply_kernel(const float* __restrict__ hpre, const float* __restrict__ scale,
                               const float* __restrict__ shift, float* __restrict__ hout) {
  int i = blockIdx.x*blockDim.x + threadIdx.x;      // one float4 per thread
  if (i >= N_NODES*HID/4) return;
  int c4 = (i*4) & 127;
  float4 v = *(const float4*)&hpre[(size_t)i*4];
  float4 sc = *(const float4*)&scale[c4];
  float4 sh = *(const float4*)&shift[c4];
  v.x = fmaxf(fmaf(v.x, sc.x, sh.x), 0.f);
  v.y = fmaxf(fmaf(v.y, sc.y, sh.y), 0.f);
  v.z = fmaxf(fmaf(v.z, sc.z, sh.z), 0.f);
  v.w = fmaxf(fmaf(v.w, sc.w, sh.w), 0.f);
  *(float4*)&hout[(size_t)i*4] = v;
}

// ---------------- node MLP 128->64->32->2 (thread per node) ----------------
__global__ __launch_bounds__(256) void nodemlp_kernel(const float* __restrict__ h,
    const float* __restrict__ w1, const float* __restrict__ b1,
    const float* __restrict__ w2, const float* __restrict__ b2,
    const float* __restrict__ w3, const float* __restrict__ b3,
    float* __restrict__ out) {
  int n = blockIdx.x*256 + threadIdx.x;
  if (n >= N_NODES) return;
  const float* hr = h + (size_t)n*HID;
  float l1[64];
  #pragma unroll
  for (int o = 0; o < 64; ++o) l1[o] = b1[o];
  for (int k4 = 0; k4 < 32; ++k4) {
    float4 hv = *(const float4*)(hr + k4*4);
    const float* wp = &w1[k4*4*64];
    #pragma unroll
    for (int o = 0; o < 64; ++o)
      l1[o] += hv.x*wp[o] + hv.y*wp[64+o] + hv.z*wp[128+o] + hv.w*wp[192+o];
  }
  #pragma unroll
  for (int o = 0; o < 64; ++o) l1[o] = fmaxf(l1[o], 0.f);
  float l2[32];
  #pragma unroll
  for (int o = 0; o < 32; ++o) l2[o] = b2[o];
  for (int k = 0; k < 64; ++k) {
    float hv = l1[k];
    const float* wp = &w2[k*32];
    #pragma unroll
    for (int o = 0; o < 32; ++o) l2[o] += hv*wp[o];
  }
  float o0 = b3[0], o1 = b3[1];
  #pragma unroll
  for (int k = 0; k < 32; ++k) {
    float hv = fmaxf(l2[k], 0.f);
    o0 += hv*w3[k*2]; o1 += hv*w3[k*2+1];
  }
  out[(size_t)n*2]   = o0;
  out[(size_t)n*2+1] = o1;
}

// ---------------- graph pooling (segmented over sorted batch) ----------------
__global__ void gmax_init_kernel(unsigned* __restrict__ gmaxenc) {
  int i = blockIdx.x*blockDim.x + threadIdx.x;
  if (i < NG*HID) gmaxenc[i] = 0x00800000u;   // enc(-FLT_MAX)
}

__global__ __launch_bounds__(128) void pool_seg_kernel(const float* __restrict__ h,
                                                       const int* __restrict__ batch,
                                                       float* __restrict__ gsum,
                                                       unsigned* __restrict__ gmaxenc,
                                                       float* __restrict__ gcnt) {
  int t = threadIdx.x;                       // column
  int r0 = blockIdx.x * POOL_CHUNK;
  int rend = min(r0 + POOL_CHUNK, N_NODES);
  if (r0 >= N_NODES) return;
  int gcur = batch[r0];
  float s = 0.f, m = -FLT_MAX;
  int cnt = 0;
  for (int r = r0; r < rend; ++r) {
    int g = batch[r];                        // wave-uniform scalar load
    if (g != gcur) {
      atomAddF(&gsum[gcur*HID + t], s);
      atomicMax(&gmaxenc[gcur*HID + t], encf(m));
      if (t == 0) atomAddF(&gcnt[gcur], (float)cnt);
      gcur = g; s = 0.f; m = -FLT_MAX; cnt = 0;
    }
    float v = h[(size_t)r*HID + t];
    s += v; m = fmaxf(m, v);
    ++cnt;
  }
  atomAddF(&gsum[gcur*HID + t], s);
  atomicMax(&gmaxenc[gcur*HID + t], encf(m));
  if (t == 0) atomAddF(&gcnt[gcur], (float)cnt);
}

// ---------------- graph MLP 256->128->64->2 (block per graph) ----------------
__global__ __launch_bounds__(128) void graphmlp_kernel(const float* __restrict__ gsum,
    const unsigned* __restrict__ gmaxenc, const float* __restrict__ gcnt,
    const float* __restrict__ gw1, const float* __restrict__ gb1,
    const float* __restrict__ gw2, const float* __restrict__ gb2,
    const float* __restrict__ gw3, const float* __restrict__ gb3,
    float* __restrict__ out) {
  __shared__ float gr[256], h1[128], h2[64];
  int g = blockIdx.x, t = threadIdx.x;
  float cnt = fmaxf(gcnt[g], 1.f);
  gr[t] = gsum[g*HID + t] / cnt;
  gr[128 + t] = decf(gmaxenc[g*HID + t]);
  __syncthreads();
  float acc = gb1[t];
  for (int k = 0; k < 256; ++k) acc += gr[k]*gw1[k*HID + t];
  h1[t] = fmaxf(acc, 0.f);
  __syncthreads();
  if (t < 64) {
    float a2 = gb2[t];
    for (int k = 0; k < 128; ++k) a2 += h1[k]*gw2[k*64 + t];
    h2[t] = fmaxf(a2, 0.f);
  }
  __syncthreads();
  if (t < 2) {
    float a3 = gb3[t];
    for (int k = 0; k < 64; ++k) a3 += h2[k]*gw3[k*2 + t];
    out[N_NODES*2 + g*2 + t] = a3;
  }
}

extern "C" void kernel_launch(void* const* d_in, const int* in_sizes, int n_in,
                              void* d_out, int out_size, void* d_ws, size_t ws_size,
                              hipStream_t stream) {
  (void)in_sizes; (void)n_in; (void)out_size; (void)ws_size;
  const float* x       = (const float*)d_in[0];
  const int*   ei      = (const int*)d_in[1];
  const float* ea      = (const float*)d_in[2];
  const int*   batch   = (const int*)d_in[3];
  const float* W       = (const float*)d_in[4];
  const float* att_src = (const float*)d_in[5];
  const float* att_dst = (const float*)d_in[6];
  const float* We      = (const float*)d_in[7];
  const float* att_e   = (const float*)d_in[8];
  // d_in[9] = bias: cancels exactly in train-mode BN (and is zeros) -> unused
  const float* gamma   = (const float*)d_in[10];
  const float* beta    = (const float*)d_in[11];
  const float* nw1 = (const float*)d_in[12]; const float* nb1 = (const float*)d_in[13];
  const float* nw2 = (const float*)d_in[14]; const float* nb2 = (const float*)d_in[15];
  const float* nw3 = (const float*)d_in[16]; const float* nb3 = (const float*)d_in[17];
  const float* gw1 = (const float*)d_in[18]; const float* gb1 = (const float*)d_in[19];
  const float* gw2 = (const float*)d_in[20]; const float* gb2 = (const float*)d_in[21];
  const float* gw3 = (const float*)d_in[22]; const float* gb3 = (const float*)d_in[23];
  float* out = (float*)d_out;

  float* p = (float*)d_ws;
  unsigned short* xh16 = (unsigned short*)p; p += (size_t)N_NODES*HC/2;  // bf16 xh (30.7MB)
  float* hbuf  = p; p += (size_t)N_NODES*HID;    // 3.84M
  float* hnext = p; p += (size_t)N_NODES*HID;    // 3.84M
  float* excsr = p; p += (size_t)N_EDGES*NH;     // 1.6M
  float* exself= p; p += (size_t)N_NODES*NH;     // 0.12M
  float* a_s   = p; p += (size_t)N_NODES*NH;
  float* a_d   = p; p += (size_t)N_NODES*NH;
  float* easum = p; p += (size_t)N_NODES*3;
  float* deg   = p; p += (size_t)N_NODES;
  float* wsrc  = p; p += NL*HID*NH;
  float* wdst  = p; p += NL*HID*NH;
  float* weatt = p; p += NL*3*NH;
  float* colsum= p; p += HID;
  float* colsq = p; p += HID;
  float* scale = p; p += HID;
  float* shift = p; p += HID;
  float* gsum  = p; p += NG*HID;
  float* gcnt  = p; p += NG;
  unsigned* gmaxenc = (unsigned*)p; p += NG*HID;
  int* rowptr  = (int*)p; p += (N_NODES + 1);
  int* fill    = (int*)p; p += N_NODES;
  int* csr_src = (int*)p; p += N_EDGES;
  int* csr_pos = (int*)p; p += N_EDGES;

  // once-per-call precompute
  hipMemsetAsync(easum, 0, (size_t)(N_NODES*3 + N_NODES)*sizeof(float), stream); // easum + deg
  prep_att_kernel<<<NL, 128, 0, stream>>>(W, att_src, att_dst, We, att_e, wsrc, wdst, weatt);
  deg_easum_kernel<<<(N_EDGES+255)/256, 256, 0, stream>>>(ei, ea, easum, deg);
  scan_kernel<<<1, 1024, 0, stream>>>(deg, rowptr, fill);
  csr_fill_kernel<<<(N_EDGES+255)/256, 256, 0, stream>>>(ei, rowptr, fill, csr_src, csr_pos);

  const float* hin = x;
  for (int l = 0; l < NL; ++l) {
    hipMemsetAsync(colsum, 0, 2*HID*sizeof(float), stream);  // colsum + colsq

    dim3 ggrid((N_NODES+63)/64, HC/64);
    gemm_xh_kernel<<<ggrid, 256, 0, stream>>>(hin, W + (size_t)l*HID*HC, xh16);
    asd_kernel<<<(N_NODES*64)/256, 256, 0, stream>>>(hin, wsrc + l*HID*NH, wdst + l*HID*NH, a_s, a_d);
    edge_ex_kernel<<<(N_TOT+255)/256, 256, 0, stream>>>(ei, ea, easum, deg, a_s, a_d,
                                                        weatt + l*3*NH, csr_pos, excsr, exself);
    agg_kernel<<<(N_NODES*64+255)/256, 256, 0, stream>>>(rowptr, csr_src, excsr, exself, xh16, hnext);
    bnstats_kernel<<<(N_NODES+63)/64, 256, 0, stream>>>(hnext, colsum, colsq);
    bnfin_kernel<<<1, 128, 0, stream>>>(colsum, colsq, gamma + l*HID, beta + l*HID, scale, shift);
    bnapply_kernel<<<(N_NODES*HID/4+255)/256, 256, 0, stream>>>(hnext, scale, shift, hbuf);
    hin = hbuf;
  }

  nodemlp_kernel<<<(N_NODES+255)/256, 256, 0, stream>>>(hbuf, nw1, nb1, nw2, nb2, nw3, nb3, out);

  hipMemsetAsync(gsum, 0, (size_t)(NG*HID + NG)*sizeof(float), stream);  // gsum + gcnt
  gmax_init_kernel<<<(NG*HID+255)/256, 256, 0, stream>>>(gmaxenc);
  pool_seg_kernel<<<(N_NODES + POOL_CHUNK - 1)/POOL_CHUNK, 128, 0, stream>>>(hbuf, batch, gsum, gmaxenc, gcnt);
  graphmlp_kernel<<<NG, 128, 0, stream>>>(gsum, gmaxenc, gcnt, gw1, gb1, gw2, gb2, gw3, gb3, out);
}

// Round 5
// 823.301 us; speedup vs baseline: 2.7086x; 1.1920x over previous
//
#include <hip/hip_runtime.h>
#include <float.h>

#define N_NODES 30000
#define N_EDGES 400000
#define N_TOT   430000   // E + N self loops
#define HID     128
#define NH      4
#define HC      512      // NH * 128
#define NL      3
#define NG      64
#define NEG_SLOPE 0.2f
#define BN_EPS 1e-5f
#define POOL_CHUNK 256
#define LDA_PAD 136      // bf16 elems per LDS row (128 + 8): 2-way max bank alias

typedef __attribute__((ext_vector_type(8))) short bf16x8;
typedef __attribute__((ext_vector_type(4))) float f32x4;

__device__ __forceinline__ float atomAddF(float* p, float v) { return unsafeAtomicAdd(p, v); }

__device__ __forceinline__ unsigned encf(float x) {
  unsigned u = __float_as_uint(x);
  return (u & 0x80000000u) ? ~u : (u | 0x80000000u);
}
__device__ __forceinline__ float decf(unsigned u) {
  return (u & 0x80000000u) ? __uint_as_float(u ^ 0x80000000u) : __uint_as_float(~u);
}
__device__ __forceinline__ unsigned short f2bf(float f) {   // RNE
  unsigned u = __float_as_uint(f);
  u += 0x7FFFu + ((u >> 16) & 1u);
  return (unsigned short)(u >> 16);
}
__device__ __forceinline__ float bf2f(unsigned short s) {
  return __uint_as_float(((unsigned)s) << 16);
}

// ---------------- attention projection precompute ----------------
__global__ void prep_att_kernel(const float* __restrict__ W, const float* __restrict__ att_src,
                                const float* __restrict__ att_dst, const float* __restrict__ We,
                                const float* __restrict__ att_e,
                                float* __restrict__ wsrc, float* __restrict__ wdst,
                                float* __restrict__ weatt) {
  int l = blockIdx.x, t = threadIdx.x;   // 128 threads
  for (int h = 0; h < NH; ++h) {
    const float* as = att_src + (size_t)(l*NH + h)*HID;
    const float* ad = att_dst + (size_t)(l*NH + h)*HID;
    const float* wr = W + (size_t)(l*HID + t)*HC + h*HID;
    float s = 0.f, d = 0.f;
    for (int c = 0; c < HID; ++c) { float w = wr[c]; s += w*as[c]; d += w*ad[c]; }
    wsrc[(l*HID + t)*NH + h] = s;
    wdst[(l*HID + t)*NH + h] = d;
  }
  if (t < 3) {
    for (int h = 0; h < NH; ++h) {
      const float* ae = att_e + (size_t)(l*NH + h)*HID;
      const float* wr = We + (size_t)(l*3 + t)*HC + h*HID;
      float s = 0.f;
      for (int c = 0; c < HID; ++c) s += wr[c]*ae[c];
      weatt[(l*3 + t)*NH + h] = s;
    }
  }
}

// Wt[l][n][k] = bf16(W[l][k][n])  — B^T layout for MFMA B-fragments
__global__ void prep_wt_kernel(const float* __restrict__ W, unsigned short* __restrict__ Wt) {
  int l = blockIdx.y;
  int idx = blockIdx.x*256 + threadIdx.x;   // over 512*128
  int n = idx >> 7, k = idx & 127;
  Wt[((size_t)l*HC + n)*HID + k] = f2bf(W[((size_t)l*HID + k)*HC + n]);
}

// in-degree and incoming-edge-attr sum (for self-loop fill_value='mean')
__global__ void deg_easum_kernel(const int* __restrict__ ei, const float* __restrict__ ea,
                                 float* __restrict__ easum, float* __restrict__ deg) {
  int e = blockIdx.x*blockDim.x + threadIdx.x;
  if (e >= N_EDGES) return;
  int d = ei[N_EDGES + e];
  atomAddF(&deg[d], 1.0f);
  atomAddF(&easum[d*3+0], ea[e*3+0]);
  atomAddF(&easum[d*3+1], ea[e*3+1]);
  atomAddF(&easum[d*3+2], ea[e*3+2]);
}

// ---------------- CSR build: rowptr = exclusive scan of deg ----------------
__global__ __launch_bounds__(1024) void scan_kernel(const float* __restrict__ deg,
                                                    int* __restrict__ rowptr,
                                                    int* __restrict__ fill) {
  __shared__ int part[1024];
  int t = threadIdx.x;
  const int CH = (N_NODES + 1023) / 1024;  // 30
  int base = t * CH;
  int s = 0;
  for (int i = 0; i < CH; ++i) {
    int n = base + i;
    if (n < N_NODES) s += (int)deg[n];
  }
  part[t] = s;
  __syncthreads();
  for (int off = 1; off < 1024; off <<= 1) {
    int v = (t >= off) ? part[t - off] : 0;
    __syncthreads();
    if (t >= off) part[t] += v;
    __syncthreads();
  }
  int prefix = (t == 0) ? 0 : part[t-1];
  for (int i = 0; i < CH; ++i) {
    int n = base + i;
    if (n < N_NODES) {
      rowptr[n] = prefix;
      fill[n] = 0;
      prefix += (int)deg[n];
    }
  }
  if (t == 1023) rowptr[N_NODES] = part[1023];
}

__global__ void csr_fill_kernel(const int* __restrict__ ei, const int* __restrict__ rowptr,
                                int* __restrict__ fill, int* __restrict__ csr_src,
                                int* __restrict__ csr_pos) {
  int e = blockIdx.x*blockDim.x + threadIdx.x;
  if (e >= N_EDGES) return;
  int s = ei[e], d = ei[N_EDGES + e];
  int pos = rowptr[d] + atomicAdd(&fill[d], 1);
  csr_src[pos] = s;
  csr_pos[e] = pos;
}

// ---------------- xh = bf16( h @ W[l] ) via MFMA: [30000,128] x [128,512] ----------------
// block tile 128(M) x 64(N); 4 waves, wave w owns rows [w*32, w*32+32), all 64 cols.
__global__ __launch_bounds__(256) void gemm_mfma_kernel(const float* __restrict__ A,
                                                        const unsigned short* __restrict__ WtL,
                                                        unsigned short* __restrict__ C) {
  __shared__ unsigned short As[128 * LDA_PAD];
  int m0 = blockIdx.x * 128, n0 = blockIdx.y * 64;
  int t = threadIdx.x;
  // stage A tile f32 -> bf16 LDS
  #pragma unroll
  for (int i = 0; i < 16; ++i) {
    int idx = t + i*256;                 // float4 index over 128x32
    int row = idx >> 5, k4 = (idx & 31) * 4;
    int gm = m0 + row;
    float4 v = (gm < N_NODES) ? *(const float4*)&A[(size_t)gm*HID + k4]
                              : make_float4(0.f,0.f,0.f,0.f);
    ushort4 o; o.x = f2bf(v.x); o.y = f2bf(v.y); o.z = f2bf(v.z); o.w = f2bf(v.w);
    *(ushort4*)&As[row*LDA_PAD + k4] = o;
  }
  __syncthreads();
  int wave = t >> 6, lane = t & 63;
  int mbase = wave * 32;
  int lrow = lane & 15, lk = (lane >> 4) * 8;
  f32x4 acc[2][4] = {};
  #pragma unroll
  for (int ks = 0; ks < 4; ++ks) {
    int k0 = ks * 32;
    bf16x8 a0 = *(const bf16x8*)&As[(mbase + lrow)*LDA_PAD + k0 + lk];
    bf16x8 a1 = *(const bf16x8*)&As[(mbase + 16 + lrow)*LDA_PAD + k0 + lk];
    #pragma unroll
    for (int nf = 0; nf < 4; ++nf) {
      bf16x8 b = *(const bf16x8*)&WtL[(size_t)(n0 + nf*16 + lrow)*HID + k0 + lk];
      acc[0][nf] = __builtin_amdgcn_mfma_f32_16x16x32_bf16(a0, b, acc[0][nf], 0, 0, 0);
      acc[1][nf] = __builtin_amdgcn_mfma_f32_16x16x32_bf16(a1, b, acc[1][nf], 0, 0, 0);
    }
  }
  int orow = (lane >> 4) * 4, ocol = lane & 15;
  #pragma unroll
  for (int mf = 0; mf < 2; ++mf) {
    #pragma unroll
    for (int r = 0; r < 4; ++r) {
      int gm = m0 + mbase + mf*16 + orow + r;
      if (gm < N_NODES) {
        #pragma unroll
        for (int nf = 0; nf < 4; ++nf)
          C[(size_t)gm*HC + n0 + nf*16 + ocol] = f2bf(acc[mf][nf][r]);
      }
    }
  }
}

// ---------------- a_s/a_d : one wave per node ----------------
__global__ __launch_bounds__(256) void asd_kernel(const float* __restrict__ hin,
                                                  const float* __restrict__ wsrcL,
                                                  const float* __restrict__ wdstL,
                                                  float* __restrict__ a_s, float* __restrict__ a_d) {
  int wid = (blockIdx.x*256 + threadIdx.x) >> 6;
  int lane = threadIdx.x & 63;
  if (wid >= N_NODES) return;
  float v0 = hin[(size_t)wid*HID + lane];
  float v1 = hin[(size_t)wid*HID + 64 + lane];
  float4 w0s = *(const float4*)&wsrcL[lane*4];
  float4 w1s = *(const float4*)&wsrcL[(64+lane)*4];
  float4 w0d = *(const float4*)&wdstL[lane*4];
  float4 w1d = *(const float4*)&wdstL[(64+lane)*4];
  float ps0 = v0*w0s.x + v1*w1s.x, ps1 = v0*w0s.y + v1*w1s.y;
  float ps2 = v0*w0s.z + v1*w1s.z, ps3 = v0*w0s.w + v1*w1s.w;
  float pd0 = v0*w0d.x + v1*w1d.x, pd1 = v0*w0d.y + v1*w1d.y;
  float pd2 = v0*w0d.z + v1*w1d.z, pd3 = v0*w0d.w + v1*w1d.w;
  #pragma unroll
  for (int off = 32; off > 0; off >>= 1) {
    ps0 += __shfl_xor(ps0, off); ps1 += __shfl_xor(ps1, off);
    ps2 += __shfl_xor(ps2, off); ps3 += __shfl_xor(ps3, off);
    pd0 += __shfl_xor(pd0, off); pd1 += __shfl_xor(pd1, off);
    pd2 += __shfl_xor(pd2, off); pd3 += __shfl_xor(pd3, off);
  }
  if (lane == 0) {
    *(float4*)&a_s[wid*4] = make_float4(ps0, ps1, ps2, ps3);
    *(float4*)&a_d[wid*4] = make_float4(pd0, pd1, pd2, pd3);
  }
}

// ---------------- edge pass: ex = exp(leakyrelu(...)) written in CSR order ----------------
__global__ void edge_ex_kernel(const int* __restrict__ ei, const float* __restrict__ ea,
                               const float* __restrict__ easum, const float* __restrict__ deg,
                               const float* __restrict__ a_s, const float* __restrict__ a_d,
                               const float* __restrict__ weattL, const int* __restrict__ csr_pos,
                               float* __restrict__ excsr, float* __restrict__ exself) {
  int e = blockIdx.x*blockDim.x + threadIdx.x;
  if (e >= N_TOT) return;
  int s, d; float e0, e1, e2;
  if (e < N_EDGES) {
    s = ei[e]; d = ei[N_EDGES + e];
    e0 = ea[e*3+0]; e1 = ea[e*3+1]; e2 = ea[e*3+2];
  } else {
    int n = e - N_EDGES; s = n; d = n;
    float inv = 1.f / fmaxf(deg[n], 1.f);
    e0 = easum[n*3+0]*inv; e1 = easum[n*3+1]*inv; e2 = easum[n*3+2]*inv;
  }
  float4 as4 = *(const float4*)&a_s[s*4];
  float4 ad4 = *(const float4*)&a_d[d*4];
  float4 w0 = *(const float4*)&weattL[0];
  float4 w1 = *(const float4*)&weattL[4];
  float4 w2 = *(const float4*)&weattL[8];
  float raw0 = as4.x + ad4.x + e0*w0.x + e1*w1.x + e2*w2.x;
  float raw1 = as4.y + ad4.y + e0*w0.y + e1*w1.y + e2*w2.y;
  float raw2 = as4.z + ad4.z + e0*w0.z + e1*w1.z + e2*w2.z;
  float raw3 = as4.w + ad4.w + e0*w0.w + e1*w1.w + e2*w2.w;
  raw0 = raw0 > 0.f ? raw0 : NEG_SLOPE*raw0;
  raw1 = raw1 > 0.f ? raw1 : NEG_SLOPE*raw1;
  raw2 = raw2 > 0.f ? raw2 : NEG_SLOPE*raw2;
  raw3 = raw3 > 0.f ? raw3 : NEG_SLOPE*raw3;
  float4 exv = make_float4(__expf(raw0), __expf(raw1), __expf(raw2), __expf(raw3));
  if (e < N_EDGES) {
    *(float4*)&excsr[(size_t)csr_pos[e]*4] = exv;
  } else {
    *(float4*)&exself[(size_t)(e - N_EDGES)*4] = exv;
  }
}

// ---------------- CSR aggregation: one wave per dst node, bf16 xh gather ----------------
__global__ __launch_bounds__(256) void agg_kernel(const int* __restrict__ rowptr,
    const int* __restrict__ csr_src, const float* __restrict__ excsr,
    const float* __restrict__ exself, const unsigned short* __restrict__ xh,
    float* __restrict__ hnext) {
  int wid = (blockIdx.x*256 + threadIdx.x) >> 6;   // dst node id
  int lane = threadIdx.x & 63;
  if (wid >= N_NODES) return;
  int p0 = rowptr[wid], p1 = rowptr[wid+1];
  int cc = lane*2;
  float a00, a01, a10, a11, a20, a21, a30, a31;
  float den0, den1, den2, den3;
  {
    float4 exv = *(const float4*)&exself[(size_t)wid*4];
    den0 = exv.x; den1 = exv.y; den2 = exv.z; den3 = exv.w;
    const unsigned short* xr = xh + (size_t)wid*HC + cc;
    ushort2 r0 = *(const ushort2*)&xr[0];
    ushort2 r1 = *(const ushort2*)&xr[128];
    ushort2 r2 = *(const ushort2*)&xr[256];
    ushort2 r3 = *(const ushort2*)&xr[384];
    a00 = exv.x*bf2f(r0.x); a01 = exv.x*bf2f(r0.y);
    a10 = exv.y*bf2f(r1.x); a11 = exv.y*bf2f(r1.y);
    a20 = exv.z*bf2f(r2.x); a21 = exv.z*bf2f(r2.y);
    a30 = exv.w*bf2f(r3.x); a31 = exv.w*bf2f(r3.y);
  }
  for (int p = p0; p < p1; ++p) {
    int s = csr_src[p];
    float4 exv = *(const float4*)&excsr[(size_t)p*4];
    den0 += exv.x; den1 += exv.y; den2 += exv.z; den3 += exv.w;
    const unsigned short* xr = xh + (size_t)s*HC + cc;
    ushort2 r0 = *(const ushort2*)&xr[0];
    ushort2 r1 = *(const ushort2*)&xr[128];
    ushort2 r2 = *(const ushort2*)&xr[256];
    ushort2 r3 = *(const ushort2*)&xr[384];
    a00 = fmaf(exv.x, bf2f(r0.x), a00); a01 = fmaf(exv.x, bf2f(r0.y), a01);
    a10 = fmaf(exv.y, bf2f(r1.x), a10); a11 = fmaf(exv.y, bf2f(r1.y), a11);
    a20 = fmaf(exv.z, bf2f(r2.x), a20); a21 = fmaf(exv.z, bf2f(r2.y), a21);
    a30 = fmaf(exv.w, bf2f(r3.x), a30); a31 = fmaf(exv.w, bf2f(r3.y), a31);
  }
  float i0 = 1.f/den0, i1 = 1.f/den1, i2 = 1.f/den2, i3 = 1.f/den3;
  float x0 = 0.25f*(a00*i0 + a10*i1 + a20*i2 + a30*i3);
  float x1 = 0.25f*(a01*i0 + a11*i1 + a21*i2 + a31*i3);
  *(float2*)&hnext[(size_t)wid*HID + cc] = make_float2(x0, x1);
}

// ---------------- BatchNorm: column sums / sumsq ----------------
__global__ void bnstats_kernel(const float* __restrict__ hpre,
                               float* __restrict__ colsum, float* __restrict__ colsq) {
  __shared__ float ssum[256], ssq[256];
  int t = threadIdx.x;
  int c = t & 127, half = t >> 7;
  int r0 = blockIdx.x * 64;
  float s = 0.f, q = 0.f;
  for (int j = half; j < 64; j += 2) {
    int r = r0 + j;
    if (r < N_NODES) { float v = hpre[(size_t)r*HID + c]; s += v; q += v*v; }
  }
  ssum[t] = s; ssq[t] = q;
  __syncthreads();
  if (half == 0) {
    atomAddF(&colsum[c], ssum[c] + ssum[c+128]);
    atomAddF(&colsq[c],  ssq[c]  + ssq[c+128]);
  }
}

__global__ void bnfin_kernel(const float* __restrict__ colsum, const float* __restrict__ colsq,
                             const float* __restrict__ gammaL, const float* __restrict__ betaL,
                             float* __restrict__ scale, float* __restrict__ shift) {
  int c = threadIdx.x;
  const float invn = 1.f / (float)N_NODES;
  float mu = colsum[c] * invn;
  float var = fmaxf(colsq[c]*invn - mu*mu, 0.f);
  float sc = gammaL[c] * rsqrtf(var + BN_EPS);
  scale[c] = sc;
  shift[c] = betaL[c] - mu*sc;
}

__global__ void bnapply_kernel(const float* __restrict__ hpre, const float* __restrict__ scale,
                               const float* __restrict__ shift, float* __restrict__ hout) {
  int i = blockIdx.x*blockDim.x + threadIdx.x;      // one float4 per thread
  if (i >= N_NODES*HID/4) return;
  int c4 = (i*4) & 127;
  float4 v = *(const float4*)&hpre[(size_t)i*4];
  float4 sc = *(const float4*)&scale[c4];
  float4 sh = *(const float4*)&shift[c4];
  v.x = fmaxf(fmaf(v.x, sc.x, sh.x), 0.f);
  v.y = fmaxf(fmaf(v.y, sc.y, sh.y), 0.f);
  v.z = fmaxf(fmaf(v.z, sc.z, sh.z), 0.f);
  v.w = fmaxf(fmaf(v.w, sc.w, sh.w), 0.f);
  *(float4*)&hout[(size_t)i*4] = v;
}

// ---------------- node MLP 128->64->32->2 (thread per node) ----------------
__global__ __launch_bounds__(256) void nodemlp_kernel(const float* __restrict__ h,
    const float* __restrict__ w1, const float* __restrict__ b1,
    const float* __restrict__ w2, const float* __restrict__ b2,
    const float* __restrict__ w3, const float* __restrict__ b3,
    float* __restrict__ out) {
  int n = blockIdx.x*256 + threadIdx.x;
  if (n >= N_NODES) return;
  const float* hr = h + (size_t)n*HID;
  float l1[64];
  #pragma unroll
  for (int o = 0; o < 64; ++o) l1[o] = b1[o];
  for (int k4 = 0; k4 < 32; ++k4) {
    float4 hv = *(const float4*)(hr + k4*4);
    const float* wp = &w1[k4*4*64];
    #pragma unroll
    for (int o = 0; o < 64; ++o)
      l1[o] += hv.x*wp[o] + hv.y*wp[64+o] + hv.z*wp[128+o] + hv.w*wp[192+o];
  }
  #pragma unroll
  for (int o = 0; o < 64; ++o) l1[o] = fmaxf(l1[o], 0.f);
  float l2[32];
  #pragma unroll
  for (int o = 0; o < 32; ++o) l2[o] = b2[o];
  for (int k = 0; k < 64; ++k) {
    float hv = l1[k];
    const float* wp = &w2[k*32];
    #pragma unroll
    for (int o = 0; o < 32; ++o) l2[o] += hv*wp[o];
  }
  float o0 = b3[0], o1 = b3[1];
  #pragma unroll
  for (int k = 0; k < 32; ++k) {
    float hv = fmaxf(l2[k], 0.f);
    o0 += hv*w3[k*2]; o1 += hv*w3[k*2+1];
  }
  out[(size_t)n*2]   = o0;
  out[(size_t)n*2+1] = o1;
}

// ---------------- graph pooling (segmented over sorted batch) ----------------
__global__ void gmax_init_kernel(unsigned* __restrict__ gmaxenc) {
  int i = blockIdx.x*blockDim.x + threadIdx.x;
  if (i < NG*HID) gmaxenc[i] = 0x00800000u;   // enc(-FLT_MAX)
}

__global__ __launch_bounds__(128) void pool_seg_kernel(const float* __restrict__ h,
                                                       const int* __restrict__ batch,
                                                       float* __restrict__ gsum,
                                                       unsigned* __restrict__ gmaxenc,
                                                       float* __restrict__ gcnt) {
  int t = threadIdx.x;                       // column
  int r0 = blockIdx.x * POOL_CHUNK;
  int rend = min(r0 + POOL_CHUNK, N_NODES);
  if (r0 >= N_NODES) return;
  int gcur = batch[r0];
  float s = 0.f, m = -FLT_MAX;
  int cnt = 0;
  for (int r = r0; r < rend; ++r) {
    int g = batch[r];                        // wave-uniform scalar load
    if (g != gcur) {
      atomAddF(&gsum[gcur*HID + t], s);
      atomicMax(&gmaxenc[gcur*HID + t], encf(m));
      if (t == 0) atomAddF(&gcnt[gcur], (float)cnt);
      gcur = g; s = 0.f; m = -FLT_MAX; cnt = 0;
    }
    float v = h[(size_t)r*HID + t];
    s += v; m = fmaxf(m, v);
    ++cnt;
  }
  atomAddF(&gsum[gcur*HID + t], s);
  atomicMax(&gmaxenc[gcur*HID + t], encf(m));
  if (t == 0) atomAddF(&gcnt[gcur], (float)cnt);
}

// ---------------- graph MLP 256->128->64->2 (block per graph) ----------------
__global__ __launch_bounds__(128) void graphmlp_kernel(const float* __restrict__ gsum,
    const unsigned* __restrict__ gmaxenc, const float* __restrict__ gcnt,
    const float* __restrict__ gw1, const float* __restrict__ gb1,
    const float* __restrict__ gw2, const float* __restrict__ gb2,
    const float* __restrict__ gw3, const float* __restrict__ gb3,
    float* __restrict__ out) {
  __shared__ float gr[256], h1[128], h2[64];
  int g = blockIdx.x, t = threadIdx.x;
  float cnt = fmaxf(gcnt[g], 1.f);
  gr[t] = gsum[g*HID + t] / cnt;
  gr[128 + t] = decf(gmaxenc[g*HID + t]);
  __syncthreads();
  float acc = gb1[t];
  for (int k = 0; k < 256; ++k) acc += gr[k]*gw1[k*HID + t];
  h1[t] = fmaxf(acc, 0.f);
  __syncthreads();
  if (t < 64) {
    float a2 = gb2[t];
    for (int k = 0; k < 128; ++k) a2 += h1[k]*gw2[k*64 + t];
    h2[t] = fmaxf(a2, 0.f);
  }
  __syncthreads();
  if (t < 2) {
    float a3 = gb3[t];
    for (int k = 0; k < 64; ++k) a3 += h2[k]*gw3[k*2 + t];
    out[N_NODES*2 + g*2 + t] = a3;
  }
}

extern "C" void kernel_launch(void* const* d_in, const int* in_sizes, int n_in,
                              void* d_out, int out_size, void* d_ws, size_t ws_size,
                              hipStream_t stream) {
  (void)in_sizes; (void)n_in; (void)out_size; (void)ws_size;
  const float* x       = (const float*)d_in[0];
  const int*   ei      = (const int*)d_in[1];
  const float* ea      = (const float*)d_in[2];
  const int*   batch   = (const int*)d_in[3];
  const float* W       = (const float*)d_in[4];
  const float* att_src = (const float*)d_in[5];
  const float* att_dst = (const float*)d_in[6];
  const float* We      = (const float*)d_in[7];
  const float* att_e   = (const float*)d_in[8];
  // d_in[9] = bias: cancels exactly in train-mode BN (and is zeros) -> unused
  const float* gamma   = (const float*)d_in[10];
  const float* beta    = (const float*)d_in[11];
  const float* nw1 = (const float*)d_in[12]; const float* nb1 = (const float*)d_in[13];
  const float* nw2 = (const float*)d_in[14]; const float* nb2 = (const float*)d_in[15];
  const float* nw3 = (const float*)d_in[16]; const float* nb3 = (const float*)d_in[17];
  const float* gw1 = (const float*)d_in[18]; const float* gb1 = (const float*)d_in[19];
  const float* gw2 = (const float*)d_in[20]; const float* gb2 = (const float*)d_in[21];
  const float* gw3 = (const float*)d_in[22]; const float* gb3 = (const float*)d_in[23];
  float* out = (float*)d_out;

  float* p = (float*)d_ws;
  unsigned short* xh16 = (unsigned short*)p; p += (size_t)N_NODES*HC/2;  // bf16 xh (30.7MB)
  float* hbuf  = p; p += (size_t)N_NODES*HID;    // 3.84M
  float* hnext = p; p += (size_t)N_NODES*HID;    // 3.84M
  float* excsr = p; p += (size_t)N_EDGES*NH;     // 1.6M
  float* exself= p; p += (size_t)N_NODES*NH;     // 0.12M
  float* a_s   = p; p += (size_t)N_NODES*NH;
  float* a_d   = p; p += (size_t)N_NODES*NH;
  float* easum = p; p += (size_t)N_NODES*3;
  float* deg   = p; p += (size_t)N_NODES;
  float* wsrc  = p; p += NL*HID*NH;
  float* wdst  = p; p += NL*HID*NH;
  float* weatt = p; p += NL*3*NH;
  float* colsum= p; p += HID;
  float* colsq = p; p += HID;
  float* scale = p; p += HID;
  float* shift = p; p += HID;
  float* gsum  = p; p += NG*HID;
  float* gcnt  = p; p += NG;
  unsigned* gmaxenc = (unsigned*)p; p += NG*HID;
  int* rowptr  = (int*)p; p += (N_NODES + 1);
  int* fill    = (int*)p; p += N_NODES;
  int* csr_src = (int*)p; p += N_EDGES;
  int* csr_pos = (int*)p; p += N_EDGES;
  unsigned short* wt16 = (unsigned short*)p; p += NL*HID*HC/2;  // bf16 W^T per layer

  // once-per-call precompute
  hipMemsetAsync(easum, 0, (size_t)(N_NODES*3 + N_NODES)*sizeof(float), stream); // easum + deg
  prep_att_kernel<<<NL, 128, 0, stream>>>(W, att_src, att_dst, We, att_e, wsrc, wdst, weatt);
  prep_wt_kernel<<<dim3(HC*HID/256, NL), 256, 0, stream>>>(W, wt16);
  deg_easum_kernel<<<(N_EDGES+255)/256, 256, 0, stream>>>(ei, ea, easum, deg);
  scan_kernel<<<1, 1024, 0, stream>>>(deg, rowptr, fill);
  csr_fill_kernel<<<(N_EDGES+255)/256, 256, 0, stream>>>(ei, rowptr, fill, csr_src, csr_pos);

  const float* hin = x;
  for (int l = 0; l < NL; ++l) {
    hipMemsetAsync(colsum, 0, 2*HID*sizeof(float), stream);  // colsum + colsq

    dim3 ggrid((N_NODES+127)/128, HC/64);
    gemm_mfma_kernel<<<ggrid, 256, 0, stream>>>(hin, wt16 + (size_t)l*HID*HC, xh16);
    asd_kernel<<<(N_NODES*64)/256, 256, 0, stream>>>(hin, wsrc + l*HID*NH, wdst + l*HID*NH, a_s, a_d);
    edge_ex_kernel<<<(N_TOT+255)/256, 256, 0, stream>>>(ei, ea, easum, deg, a_s, a_d,
                                                        weatt + l*3*NH, csr_pos, excsr, exself);
    agg_kernel<<<(N_NODES*64+255)/256, 256, 0, stream>>>(rowptr, csr_src, excsr, exself, xh16, hnext);
    bnstats_kernel<<<(N_NODES+63)/64, 256, 0, stream>>>(hnext, colsum, colsq);
    bnfin_kernel<<<1, 128, 0, stream>>>(colsum, colsq, gamma + l*HID, beta + l*HID, scale, shift);
    bnapply_kernel<<<(N_NODES*HID/4+255)/256, 256, 0, stream>>>(hnext, scale, shift, hbuf);
    hin = hbuf;
  }

  nodemlp_kernel<<<(N_NODES+255)/256, 256, 0, stream>>>(hbuf, nw1, nb1, nw2, nb2, nw3, nb3, out);

  hipMemsetAsync(gsum, 0, (size_t)(NG*HID + NG)*sizeof(float), stream);  // gsum + gcnt
  gmax_init_kernel<<<(NG*HID+255)/256, 256, 0, stream>>>(gmaxenc);
  pool_seg_kernel<<<(N_NODES + POOL_CHUNK - 1)/POOL_CHUNK, 128, 0, stream>>>(hbuf, batch, gsum, gmaxenc, gcnt);
  graphmlp_kernel<<<NG, 128, 0, stream>>>(gsum, gmaxenc, gcnt, gw1, gb1, gw2, gb2, gw3, gb3, out);
}